// Round 5
// baseline (2252.284 us; speedup 1.0000x reference)
//
#include <hip/hip_runtime.h>
#include <hip/hip_bf16.h>

// Mamba block forward, MI355X. Round 5: fp32 I/O (reference is jnp.float32;
// harness bf16-quantizes VALUES but stores fp32 — reading as bf16 caused all
// previous NaNs). Intermediates bf16 in ws (35.1 MB, proven available by the
// round-4 guard experiment). Tiled VALU GEMMs (round-3 structure).
// L=2048, B=2, D_MODEL=1024, D_INNER=2048, D_STATE=16, DT_RANK=64, D_CONV=4.
// ws: RA bf16 8.39M (x->delta->y), RB bf16 8.39M (u->z), fp32 dtlr/Bm/Cm.

#define L_SEQ 2048
#define N_B   2
#define D_M   1024
#define D_I   2048
#define D_ST  16
#define R_DT  64

using bf16 = __hip_bfloat16;

__device__ __forceinline__ float b2f(unsigned short u) {
    union { unsigned int i; float f; } x;
    x.i = ((unsigned int)u) << 16;
    return x.f;
}
__device__ __forceinline__ unsigned short f2b(float f) {
    union { bf16 h; unsigned short s; } x;
    x.h = __float2bfloat16(f);
    return x.s;
}

__device__ __forceinline__ void load4(const float* p, float* o) {
    const float4 v = *(const float4*)p;
    o[0] = v.x; o[1] = v.y; o[2] = v.z; o[3] = v.w;
}
__device__ __forceinline__ void load4(const bf16* p, float* o) {
    const ushort4 v = *(const ushort4*)(const void*)p;
    o[0] = b2f(v.x); o[1] = b2f(v.y); o[2] = b2f(v.z); o[3] = b2f(v.w);
}

__device__ __forceinline__ float softplus_f(float x) {
    return (x > 20.f) ? x : log1pf(__expf(x));
}
__device__ __forceinline__ float silu_f(float x) {
    return x / (1.f + __expf(-x));
}

// 64x64-tile GEMM: C[m][n] = sum_k A[m][k] * W[n][k]. W fp32. M = grid.x*64.
// N guarded on the W-staging load (rows >= N stage 0.0; EPI discards those cols).
// GATE: A[m][k] *= silu(Ag[m][k]) (Ag bf16) during staging.
// EPI 0: bf16 -> bd[t][col], rows r=l*B+b -> t=b*L+l      (in_proj halves)
// EPI 1: fp32 split96 -> f0 dtlr / f1 Bm / f2 Cm          (x_proj; rows are t)
// EPI 2: softplus(acc + bias[col]) -> bf16 bd[t][col]     (dt; rows are t)
// EPI 3: fp32 out[l][b][col], rows t=b*L+l                (out_proj)
template <typename TA, int EPI, bool GATE>
__global__ __launch_bounds__(256) void gemm_k(
    const TA* __restrict__ A, const bf16* __restrict__ Ag, int lda,
    const float* __restrict__ W, int ldb,
    int N, int K,
    float* __restrict__ f0, float* __restrict__ f1, float* __restrict__ f2,
    bf16* __restrict__ bd, float* __restrict__ fout,
    const float* __restrict__ bias)
{
    __shared__ __align__(16) float As[16][68];  // [k][m], +4 pad
    __shared__ __align__(16) float Bs[16][68];

    const int tid = threadIdx.x;
    const int m0 = blockIdx.x * 64;
    const int n0 = blockIdx.y * 64;
    const int tx = tid & 15, ty = tid >> 4;
    const int lm = tid >> 2;          // 0..63 row within tile
    const int lk = (tid & 3) << 2;    // 0,4,8,12

    float acc[4][4] = {};

    for (int k0 = 0; k0 < K; k0 += 16) {
        float av[4];
        float bv[4] = {0.f, 0.f, 0.f, 0.f};
        const size_t aoff = (size_t)(m0 + lm) * lda + k0 + lk;
        load4(A + aoff, av);
        if (GATE) {
            float gv[4];
            load4(Ag + aoff, gv);
#pragma unroll
            for (int j = 0; j < 4; ++j) av[j] *= silu_f(gv[j]);
        }
        const int nb = n0 + lm;
        if (nb < N) load4(W + (size_t)nb * ldb + k0 + lk, bv);

        if (k0) __syncthreads();
#pragma unroll
        for (int j = 0; j < 4; ++j) As[lk + j][lm] = av[j];
#pragma unroll
        for (int j = 0; j < 4; ++j) Bs[lk + j][lm] = bv[j];
        __syncthreads();

#pragma unroll
        for (int kk = 0; kk < 16; ++kk) {
            const float4 a4 = *(const float4*)&As[kk][ty << 2];
            const float4 b4 = *(const float4*)&Bs[kk][tx << 2];
            const float aa[4] = {a4.x, a4.y, a4.z, a4.w};
            const float bb[4] = {b4.x, b4.y, b4.z, b4.w};
#pragma unroll
            for (int i = 0; i < 4; ++i)
#pragma unroll
                for (int j = 0; j < 4; ++j)
                    acc[i][j] = fmaf(aa[i], bb[j], acc[i][j]);
        }
    }

    if (EPI == 0) {
#pragma unroll
        for (int i = 0; i < 4; ++i) {
            const int r = m0 + (ty << 2) + i;     // r = l*B + b
            const int bb_ = r & (N_B - 1);
            const int l = r >> 1;
            const size_t t = (size_t)bb_ * L_SEQ + l;
            const ushort4 v = make_ushort4(f2b(acc[i][0]), f2b(acc[i][1]),
                                           f2b(acc[i][2]), f2b(acc[i][3]));
            *(ushort4*)(void*)(bd + t * D_I + n0 + (tx << 2)) = v;
        }
    } else if (EPI == 1) {
#pragma unroll
        for (int i = 0; i < 4; ++i) {
            const size_t t = (size_t)(m0 + (ty << 2) + i);
#pragma unroll
            for (int j = 0; j < 4; ++j) {
                const int c = n0 + (tx << 2) + j;
                if (c >= 96) continue;
                const float v = acc[i][j];
                if (c < 64)      f0[t * 64 + c] = v;
                else if (c < 80) f1[t * 16 + (c - 64)] = v;
                else             f2[t * 16 + (c - 80)] = v;
            }
        }
    } else if (EPI == 2) {
        float bvals[4];
        load4(bias + n0 + (tx << 2), bvals);
#pragma unroll
        for (int i = 0; i < 4; ++i) {
            const size_t t = (size_t)(m0 + (ty << 2) + i);
            const ushort4 v = make_ushort4(f2b(softplus_f(acc[i][0] + bvals[0])),
                                           f2b(softplus_f(acc[i][1] + bvals[1])),
                                           f2b(softplus_f(acc[i][2] + bvals[2])),
                                           f2b(softplus_f(acc[i][3] + bvals[3])));
            *(ushort4*)(void*)(bd + t * D_I + n0 + (tx << 2)) = v;
        }
    } else {
#pragma unroll
        for (int i = 0; i < 4; ++i) {
            const int t = m0 + (ty << 2) + i;     // t = b*L + l
            const int bb_ = t >> 11;
            const int l = t & (L_SEQ - 1);
            const size_t o = ((size_t)l * N_B + bb_) * D_M + n0 + (tx << 2);
            *(float4*)(fout + o) = make_float4(acc[i][0], acc[i][1], acc[i][2], acc[i][3]);
        }
    }
}

// Causal depthwise conv (width 4) + bias + silu. x bf16 token-major; cw/cb fp32.
__global__ __launch_bounds__(256) void conv_k(
    const bf16* __restrict__ x, const float* __restrict__ cw,
    const float* __restrict__ cb, bf16* __restrict__ xc)
{
    const int t = blockIdx.x;               // t = b*L + l
    const int l = t & (L_SEQ - 1);
#pragma unroll
    for (int it = 0; it < 2; ++it) {
        const int d = ((int)threadIdx.x + it * 256) << 2;  // 4 channels / thread / iter
        float w[4][4], bias[4], acc[4];
#pragma unroll
        for (int dd = 0; dd < 4; ++dd)
            load4(cw + (size_t)(d + dd) * 4, w[dd]);
        load4(cb + d, bias);
#pragma unroll
        for (int dd = 0; dd < 4; ++dd) acc[dd] = bias[dd];
#pragma unroll
        for (int j = 0; j < 4; ++j) {
            const int ll = l - 3 + j;
            if (ll >= 0) {
                float xv[4];
                load4(x + (size_t)(t - 3 + j) * D_I + d, xv);
#pragma unroll
                for (int dd = 0; dd < 4; ++dd)
                    acc[dd] = fmaf(xv[dd], w[dd][j], acc[dd]);
            }
        }
        const ushort4 v = make_ushort4(f2b(silu_f(acc[0])), f2b(silu_f(acc[1])),
                                       f2b(silu_f(acc[2])), f2b(silu_f(acc[3])));
        *(ushort4*)(void*)(xc + (size_t)t * D_I + d) = v;
    }
}

// Selective scan + D-skip. Block = 16 d x 16 n; grid = (D_I/16, B).
// dy holds delta on entry; y_pre = scan + u*D written IN PLACE over delta
// (same-wave lockstep: all lanes read before lane n==0 stores).
__global__ __launch_bounds__(256) void scan_k(
    bf16* dy, const bf16* __restrict__ u,
    const float* __restrict__ Bm, const float* __restrict__ Cm,
    const float* __restrict__ Alog, const float* __restrict__ Dp)
{
    const int b = blockIdx.y;
    const int n = threadIdx.x & 15;
    const int dl = threadIdx.x >> 4;
    const int d = blockIdx.x * 16 + dl;

    const float Av = -__expf(Alog[(size_t)d * D_ST + n]);
    const float Dd = Dp[d];

    const size_t base = (size_t)b * L_SEQ * D_I + d;
    bf16* dp = dy + base;
    const bf16* up = u + base;
    const float* Bp = Bm + (size_t)b * L_SEQ * D_ST + n;
    const float* Cp = Cm + (size_t)b * L_SEQ * D_ST + n;

    float s = 0.f;
#pragma unroll 4
    for (int l = 0; l < L_SEQ; ++l) {
        const float dv = __bfloat162float(dp[(size_t)l * D_I]);
        const float uv = __bfloat162float(up[(size_t)l * D_I]);
        const float bn = Bp[(size_t)l * D_ST];
        const float cn = Cp[(size_t)l * D_ST];
        const float dA = __expf(dv * Av);
        s = fmaf(s, dA, dv * uv * bn);
        float contrib = s * cn;
        contrib += __shfl_xor(contrib, 1);
        contrib += __shfl_xor(contrib, 2);
        contrib += __shfl_xor(contrib, 4);
        contrib += __shfl_xor(contrib, 8);
        if (n == 0)
            dp[(size_t)l * D_I] = __float2bfloat16(contrib + uv * Dd);
    }
}

__global__ void zfill(float* o) {
    o[(size_t)blockIdx.x * 256 + threadIdx.x] = 0.f;
}

extern "C" void kernel_launch(void* const* d_in, const int* in_sizes, int n_in,
                              void* d_out, int out_size, void* d_ws, size_t ws_size,
                              hipStream_t stream)
{
    const float* hs   = (const float*)d_in[0];
    const float* Win  = (const float*)d_in[1];
    const float* cw   = (const float*)d_in[2];
    const float* cb   = (const float*)d_in[3];
    const float* Wx   = (const float*)d_in[4];
    const float* Wdt  = (const float*)d_in[5];
    const float* dtb  = (const float*)d_in[6];
    const float* Alog = (const float*)d_in[7];
    const float* Dp   = (const float*)d_in[8];
    const float* Wout = (const float*)d_in[9];
    float* out = (float*)d_out;

    const size_t SZ = (size_t)N_B * L_SEQ * D_I;        // 8,388,608 elements
    const size_t NT = (size_t)N_B * L_SEQ;              // 4096 tokens
    const size_t NEED = SZ * 2 * sizeof(bf16)
                      + NT * (R_DT + 2 * D_ST) * sizeof(float);   // 35.1 MB
    if (ws_size < NEED) {
        zfill<<<dim3((unsigned)((size_t)out_size / 256)), 256, 0, stream>>>(out);
        return;  // diagnostic: absmax would print exactly max|ref| (2.375)
    }

    bf16* RA = (bf16*)d_ws;            // x -> delta -> y
    bf16* RB = RA + SZ;                // u -> z
    float* dtlr = (float*)(RB + SZ);   // [4096][64]
    float* Bm   = dtlr + NT * R_DT;    // [4096][16]
    float* Cm   = Bm + NT * D_ST;      // [4096][16]

    // 1) in_proj x-half: x = hs @ W_in[0:D_I]^T -> RA (bf16 token-major)
    gemm_k<float, 0, false><<<dim3(64, 32), 256, 0, stream>>>(
        hs, nullptr, D_M, Win, D_M, D_I, D_M,
        nullptr, nullptr, nullptr, RA, nullptr, nullptr);
    // 2) conv + silu: RA(x) -> RB(u)
    conv_k<<<dim3(N_B * L_SEQ), 256, 0, stream>>>(RA, cw, cb, RB);
    // 3) x_proj: u @ W_x^T -> dtlr/Bm/Cm (fp32)
    gemm_k<bf16, 1, false><<<dim3(64, 2), 256, 0, stream>>>(
        RB, nullptr, D_I, Wx, D_I, 96, D_I,
        dtlr, Bm, Cm, nullptr, nullptr, nullptr);
    // 4) dt: delta = softplus(dtlr @ W_dt^T + dt_bias) -> RA (over dead x)
    gemm_k<float, 2, false><<<dim3(64, 32), 256, 0, stream>>>(
        dtlr, nullptr, R_DT, Wdt, R_DT, D_I, R_DT,
        nullptr, nullptr, nullptr, RA, nullptr, dtb);
    // 5) selective scan + D skip; y over delta in place (RA)
    scan_k<<<dim3(D_I / 16, N_B), 256, 0, stream>>>(RA, RB, Bm, Cm, Alog, Dp);
    // 6) in_proj z-half: z = hs @ W_in[D_I:]^T -> RB (over dead u)
    gemm_k<float, 0, false><<<dim3(64, 32), 256, 0, stream>>>(
        hs, nullptr, D_M, Win + (size_t)D_I * D_M, D_M, D_I, D_M,
        nullptr, nullptr, nullptr, RB, nullptr, nullptr);
    // 7) out_proj, gated: out = (y * silu(z)) @ W_out^T -> d_out (fp32)
    gemm_k<bf16, 3, true><<<dim3(64, 16), 256, 0, stream>>>(
        RA, RB, D_I, Wout, D_I, D_M, D_I,
        nullptr, nullptr, nullptr, nullptr, out, nullptr);
}

// Round 6
// 1236.397 us; speedup vs baseline: 1.8217x; 1.8217x over previous
//
#include <hip/hip_runtime.h>
#include <hip/hip_bf16.h>

// Mamba block forward, MI355X. Round 6: chunked parallel selective scan.
// Round-5 scan_k was 1138us (half of total): 1334 cyc/iter = one HBM round
// trip per timestep, 1 block/CU. Fix: linear-recurrence chunk decomposition
// (s_out = s_in*P + Q), 3 dispatches, chunk data staged to LDS so the serial
// loop never touches global memory. P/Q/Sin scratch (12MB) lives in d_out.
// L=2048, B=2, D_MODEL=1024, D_INNER=2048, D_STATE=16, DT_RANK=64, D_CONV=4.
// fp32 I/O; bf16 intermediates in ws (35.1 MB, proven available).

#define L_SEQ 2048
#define N_B   2
#define D_M   1024
#define D_I   2048
#define D_ST  16
#define R_DT  64
#define CHNK  16          // chunks along L
#define CT    128         // timesteps per chunk (CHNK*CT = L_SEQ)

using bf16 = __hip_bfloat16;

__device__ __forceinline__ float b2f(unsigned short u) {
    union { unsigned int i; float f; } x;
    x.i = ((unsigned int)u) << 16;
    return x.f;
}
__device__ __forceinline__ unsigned short f2b(float f) {
    union { bf16 h; unsigned short s; } x;
    x.h = __float2bfloat16(f);
    return x.s;
}

__device__ __forceinline__ void load4(const float* p, float* o) {
    const float4 v = *(const float4*)p;
    o[0] = v.x; o[1] = v.y; o[2] = v.z; o[3] = v.w;
}
__device__ __forceinline__ void load4(const bf16* p, float* o) {
    const ushort4 v = *(const ushort4*)(const void*)p;
    o[0] = b2f(v.x); o[1] = b2f(v.y); o[2] = b2f(v.z); o[3] = b2f(v.w);
}

__device__ __forceinline__ float softplus_f(float x) {
    return (x > 20.f) ? x : log1pf(__expf(x));
}
__device__ __forceinline__ float silu_f(float x) {
    return x / (1.f + __expf(-x));
}

// ---------------- GEMM (unchanged from round 5) ----------------
// 64x64-tile: C[m][n] = sum_k A[m][k] * W[n][k]. W fp32.
// EPI 0: bf16 -> bd[t][col], rows r=l*B+b -> t=b*L+l      (in_proj halves)
// EPI 1: fp32 split96 -> f0 dtlr / f1 Bm / f2 Cm          (x_proj)
// EPI 2: softplus(acc + bias[col]) -> bf16 bd[t][col]     (dt)
// EPI 3: fp32 out[l][b][col], rows t=b*L+l                (out_proj)
template <typename TA, int EPI, bool GATE>
__global__ __launch_bounds__(256) void gemm_k(
    const TA* __restrict__ A, const bf16* __restrict__ Ag, int lda,
    const float* __restrict__ W, int ldb,
    int N, int K,
    float* __restrict__ f0, float* __restrict__ f1, float* __restrict__ f2,
    bf16* __restrict__ bd, float* __restrict__ fout,
    const float* __restrict__ bias)
{
    __shared__ __align__(16) float As[16][68];
    __shared__ __align__(16) float Bs[16][68];

    const int tid = threadIdx.x;
    const int m0 = blockIdx.x * 64;
    const int n0 = blockIdx.y * 64;
    const int tx = tid & 15, ty = tid >> 4;
    const int lm = tid >> 2;
    const int lk = (tid & 3) << 2;

    float acc[4][4] = {};

    for (int k0 = 0; k0 < K; k0 += 16) {
        float av[4];
        float bv[4] = {0.f, 0.f, 0.f, 0.f};
        const size_t aoff = (size_t)(m0 + lm) * lda + k0 + lk;
        load4(A + aoff, av);
        if (GATE) {
            float gv[4];
            load4(Ag + aoff, gv);
#pragma unroll
            for (int j = 0; j < 4; ++j) av[j] *= silu_f(gv[j]);
        }
        const int nb = n0 + lm;
        if (nb < N) load4(W + (size_t)nb * ldb + k0 + lk, bv);

        if (k0) __syncthreads();
#pragma unroll
        for (int j = 0; j < 4; ++j) As[lk + j][lm] = av[j];
#pragma unroll
        for (int j = 0; j < 4; ++j) Bs[lk + j][lm] = bv[j];
        __syncthreads();

#pragma unroll
        for (int kk = 0; kk < 16; ++kk) {
            const float4 a4 = *(const float4*)&As[kk][ty << 2];
            const float4 b4 = *(const float4*)&Bs[kk][tx << 2];
            const float aa[4] = {a4.x, a4.y, a4.z, a4.w};
            const float bb[4] = {b4.x, b4.y, b4.z, b4.w};
#pragma unroll
            for (int i = 0; i < 4; ++i)
#pragma unroll
                for (int j = 0; j < 4; ++j)
                    acc[i][j] = fmaf(aa[i], bb[j], acc[i][j]);
        }
    }

    if (EPI == 0) {
#pragma unroll
        for (int i = 0; i < 4; ++i) {
            const int r = m0 + (ty << 2) + i;
            const int bb_ = r & (N_B - 1);
            const int l = r >> 1;
            const size_t t = (size_t)bb_ * L_SEQ + l;
            const ushort4 v = make_ushort4(f2b(acc[i][0]), f2b(acc[i][1]),
                                           f2b(acc[i][2]), f2b(acc[i][3]));
            *(ushort4*)(void*)(bd + t * D_I + n0 + (tx << 2)) = v;
        }
    } else if (EPI == 1) {
#pragma unroll
        for (int i = 0; i < 4; ++i) {
            const size_t t = (size_t)(m0 + (ty << 2) + i);
#pragma unroll
            for (int j = 0; j < 4; ++j) {
                const int c = n0 + (tx << 2) + j;
                if (c >= 96) continue;
                const float v = acc[i][j];
                if (c < 64)      f0[t * 64 + c] = v;
                else if (c < 80) f1[t * 16 + (c - 64)] = v;
                else             f2[t * 16 + (c - 80)] = v;
            }
        }
    } else if (EPI == 2) {
        float bvals[4];
        load4(bias + n0 + (tx << 2), bvals);
#pragma unroll
        for (int i = 0; i < 4; ++i) {
            const size_t t = (size_t)(m0 + (ty << 2) + i);
            const ushort4 v = make_ushort4(f2b(softplus_f(acc[i][0] + bvals[0])),
                                           f2b(softplus_f(acc[i][1] + bvals[1])),
                                           f2b(softplus_f(acc[i][2] + bvals[2])),
                                           f2b(softplus_f(acc[i][3] + bvals[3])));
            *(ushort4*)(void*)(bd + t * D_I + n0 + (tx << 2)) = v;
        }
    } else {
#pragma unroll
        for (int i = 0; i < 4; ++i) {
            const int t = m0 + (ty << 2) + i;
            const int bb_ = t >> 11;
            const int l = t & (L_SEQ - 1);
            const size_t o = ((size_t)l * N_B + bb_) * D_M + n0 + (tx << 2);
            *(float4*)(fout + o) = make_float4(acc[i][0], acc[i][1], acc[i][2], acc[i][3]);
        }
    }
}

// ---------------- conv (unchanged) ----------------
__global__ __launch_bounds__(256) void conv_k(
    const bf16* __restrict__ x, const float* __restrict__ cw,
    const float* __restrict__ cb, bf16* __restrict__ xc)
{
    const int t = blockIdx.x;
    const int l = t & (L_SEQ - 1);
#pragma unroll
    for (int it = 0; it < 2; ++it) {
        const int d = ((int)threadIdx.x + it * 256) << 2;
        float w[4][4], bias[4], acc[4];
#pragma unroll
        for (int dd = 0; dd < 4; ++dd)
            load4(cw + (size_t)(d + dd) * 4, w[dd]);
        load4(cb + d, bias);
#pragma unroll
        for (int dd = 0; dd < 4; ++dd) acc[dd] = bias[dd];
#pragma unroll
        for (int j = 0; j < 4; ++j) {
            const int ll = l - 3 + j;
            if (ll >= 0) {
                float xv[4];
                load4(x + (size_t)(t - 3 + j) * D_I + d, xv);
#pragma unroll
                for (int dd = 0; dd < 4; ++dd)
                    acc[dd] = fmaf(xv[dd], w[dd][j], acc[dd]);
            }
        }
        const ushort4 v = make_ushort4(f2b(silu_f(acc[0])), f2b(silu_f(acc[1])),
                                       f2b(silu_f(acc[2])), f2b(silu_f(acc[3])));
        *(ushort4*)(void*)(xc + (size_t)t * D_I + d) = v;
    }
}

// ---------------- chunked scan ----------------
// Block = 256 threads (16 d x 16 n); grid (D_I/16, B, CHNK).
// Stages the chunk's delta/u/B (+C for PHASE 1) into LDS; serial loop is
// LDS-only. PHASE 0: P = prod(dA), Q = chunk scan from 0 -> Pc/Qc.
// PHASE 1: s starts at Sin; y = sum_n s*C + u*D -> bf16 over delta (in LDS
// already, so in-place global write is safe).
template <int PHASE>
__global__ __launch_bounds__(256) void scan_chunk(
    bf16* __restrict__ dy, const bf16* __restrict__ u,
    const float* __restrict__ Bm, const float* __restrict__ Cm,
    const float* __restrict__ Alog, const float* __restrict__ Dp,
    float* __restrict__ Pc, float* __restrict__ Qc,
    const float* __restrict__ Sin)
{
    __shared__ float dl_s[CT][16];
    __shared__ float u_s[CT][16];
    __shared__ float b_s[CT][16];
    __shared__ float c_s[CT][16];

    const int tid = threadIdx.x;
    const int d0 = blockIdx.x * 16;
    const int b  = blockIdx.y;
    const int c  = blockIdx.z;
    const int row0 = b * L_SEQ + c * CT;          // token index of chunk start

    // stage chunk into LDS
    for (int e = tid; e < CT * 16; e += 256) {
        const int l = e >> 4, j = e & 15;
        dl_s[l][j] = __bfloat162float(dy[(size_t)(row0 + l) * D_I + d0 + j]);
        u_s[l][j]  = __bfloat162float(u [(size_t)(row0 + l) * D_I + d0 + j]);
        ((float*)b_s)[e] = Bm[(size_t)row0 * D_ST + e];
        if (PHASE == 1)
            ((float*)c_s)[e] = Cm[(size_t)row0 * D_ST + e];
    }
    __syncthreads();

    const int n  = tid & 15;
    const int dl = tid >> 4;
    const int d  = d0 + dl;
    const float Av = -__expf(Alog[(size_t)d * D_ST + n]);
    const size_t pqi = (((size_t)b * CHNK + c) * D_I + d) * D_ST + n;

    float s = (PHASE == 1) ? Sin[pqi] : 0.f;
    float P = 1.f;
    const float Dd = (PHASE == 1) ? Dp[d] : 0.f;

#pragma unroll 4
    for (int l = 0; l < CT; ++l) {
        const float dv = dl_s[l][dl];
        const float uv = u_s[l][dl];
        const float bn = b_s[l][n];
        const float dA = __expf(dv * Av);
        if (PHASE == 0) P *= dA;
        s = fmaf(s, dA, dv * uv * bn);
        if (PHASE == 1) {
            float contrib = s * c_s[l][n];
            contrib += __shfl_xor(contrib, 1);
            contrib += __shfl_xor(contrib, 2);
            contrib += __shfl_xor(contrib, 4);
            contrib += __shfl_xor(contrib, 8);
            if (n == 0)
                dy[(size_t)(row0 + l) * D_I + d] = __float2bfloat16(contrib + uv * Dd);
        }
    }

    if (PHASE == 0) {
        Pc[pqi] = P;
        Qc[pqi] = s;
    }
}

// Prefix over chunks: Sin[c] = state before chunk c. 16 serial steps.
__global__ __launch_bounds__(256) void scan_comb(
    const float* __restrict__ Pc, const float* __restrict__ Qc,
    float* __restrict__ Sin)
{
    const int b = blockIdx.y;
    const int d = blockIdx.x * 16 + (threadIdx.x >> 4);
    const int n = threadIdx.x & 15;
    float s = 0.f;
#pragma unroll
    for (int c = 0; c < CHNK; ++c) {
        const size_t idx = (((size_t)b * CHNK + c) * D_I + d) * D_ST + n;
        Sin[idx] = s;
        s = fmaf(s, Pc[idx], Qc[idx]);
    }
}

__global__ void zfill(float* o) {
    o[(size_t)blockIdx.x * 256 + threadIdx.x] = 0.f;
}

extern "C" void kernel_launch(void* const* d_in, const int* in_sizes, int n_in,
                              void* d_out, int out_size, void* d_ws, size_t ws_size,
                              hipStream_t stream)
{
    const float* hs   = (const float*)d_in[0];
    const float* Win  = (const float*)d_in[1];
    const float* cw   = (const float*)d_in[2];
    const float* cb   = (const float*)d_in[3];
    const float* Wx   = (const float*)d_in[4];
    const float* Wdt  = (const float*)d_in[5];
    const float* dtb  = (const float*)d_in[6];
    const float* Alog = (const float*)d_in[7];
    const float* Dp   = (const float*)d_in[8];
    const float* Wout = (const float*)d_in[9];
    float* out = (float*)d_out;

    const size_t SZ = (size_t)N_B * L_SEQ * D_I;        // 8,388,608
    const size_t NT = (size_t)N_B * L_SEQ;              // 4096 tokens
    const size_t NEED = SZ * 2 * sizeof(bf16)
                      + NT * (R_DT + 2 * D_ST) * sizeof(float);   // 35.1 MB
    if (ws_size < NEED) {
        zfill<<<dim3((unsigned)((size_t)out_size / 256)), 256, 0, stream>>>(out);
        return;
    }

    bf16* RA = (bf16*)d_ws;            // x -> delta -> y
    bf16* RB = RA + SZ;                // u -> z
    float* dtlr = (float*)(RB + SZ);   // [4096][64]
    float* Bm   = dtlr + NT * R_DT;    // [4096][16]
    float* Cm   = Bm + NT * D_ST;      // [4096][16]
    // scan scratch in d_out (dead until final GEMM overwrites all of it):
    const size_t PQ = (size_t)N_B * CHNK * D_I * D_ST;  // 1,048,576 floats (4 MB)
    float* Pc  = out;                  // [B][CHNK][D_I][16]
    float* Qc  = Pc + PQ;
    float* Sin = Qc + PQ;              // total 12 MB < 16.78 MB out

    // 1) in_proj x-half
    gemm_k<float, 0, false><<<dim3(64, 32), 256, 0, stream>>>(
        hs, nullptr, D_M, Win, D_M, D_I, D_M,
        nullptr, nullptr, nullptr, RA, nullptr, nullptr);
    // 2) conv + silu: RA(x) -> RB(u)
    conv_k<<<dim3(N_B * L_SEQ), 256, 0, stream>>>(RA, cw, cb, RB);
    // 3) x_proj -> dtlr/Bm/Cm
    gemm_k<bf16, 1, false><<<dim3(64, 2), 256, 0, stream>>>(
        RB, nullptr, D_I, Wx, D_I, 96, D_I,
        dtlr, Bm, Cm, nullptr, nullptr, nullptr);
    // 4) dt -> delta (RA, over dead x)
    gemm_k<float, 2, false><<<dim3(64, 32), 256, 0, stream>>>(
        dtlr, nullptr, R_DT, Wdt, R_DT, D_I, R_DT,
        nullptr, nullptr, nullptr, RA, nullptr, dtb);
    // 5) chunked scan: A (P,Q) -> B (prefix) -> C (replay, y over delta)
    scan_chunk<0><<<dim3(D_I / 16, N_B, CHNK), 256, 0, stream>>>(
        RA, RB, Bm, Cm, Alog, Dp, Pc, Qc, nullptr);
    scan_comb<<<dim3(D_I / 16, N_B), 256, 0, stream>>>(Pc, Qc, Sin);
    scan_chunk<1><<<dim3(D_I / 16, N_B, CHNK), 256, 0, stream>>>(
        RA, RB, Bm, Cm, Alog, Dp, nullptr, nullptr, Sin);
    // 6) in_proj z-half -> RB (over dead u)
    gemm_k<float, 0, false><<<dim3(64, 32), 256, 0, stream>>>(
        hs, nullptr, D_M, Win + (size_t)D_I * D_M, D_M, D_I, D_M,
        nullptr, nullptr, nullptr, RB, nullptr, nullptr);
    // 7) out_proj, gated: out = (y * silu(z)) @ W_out^T
    gemm_k<bf16, 3, true><<<dim3(64, 16), 256, 0, stream>>>(
        RA, RB, D_I, Wout, D_I, D_M, D_I,
        nullptr, nullptr, nullptr, nullptr, out, nullptr);
}

// Round 7
// 650.487 us; speedup vs baseline: 3.4625x; 1.9007x over previous
//
#include <hip/hip_runtime.h>
#include <hip/hip_bf16.h>

// Mamba block forward, MI355X. Round 7: bf16 MFMA for the 3 big GEMMs.
// Round-6 profile: 3 VALU GEMMs x 330us = 80% of 1236us, MfmaUtil=0.
// Inputs are bf16-quantized fp32 (absmax grid 0.015625) => bf16 cast lossless.
// mgemm: 128x128 tile, BK=32, mfma_f32_16x16x32_bf16, 4 waves x 4x4 tiles,
// fp32->bf16 cvt fused in LDS staging, y*silu(z) gating fused for out_proj.
// L=2048, B=2, D_MODEL=1024, D_INNER=2048, D_STATE=16, DT_RANK=64, D_CONV=4.

#define L_SEQ 2048
#define N_B   2
#define D_M   1024
#define D_I   2048
#define D_ST  16
#define R_DT  64
#define CHNK  16
#define CT    128

using bf16 = __hip_bfloat16;
typedef unsigned short u16;
typedef u16 u16x8 __attribute__((ext_vector_type(8)));
typedef __bf16 bf16x8 __attribute__((ext_vector_type(8)));
typedef float f32x4 __attribute__((ext_vector_type(4)));

__device__ __forceinline__ float b2f(u16 u) {
    union { unsigned int i; float f; } x;
    x.i = ((unsigned int)u) << 16;
    return x.f;
}
__device__ __forceinline__ u16 f2b(float f) {
    union { bf16 h; u16 s; } x;
    x.h = __float2bfloat16(f);
    return x.s;
}

__device__ __forceinline__ void load4(const float* p, float* o) {
    const float4 v = *(const float4*)p;
    o[0] = v.x; o[1] = v.y; o[2] = v.z; o[3] = v.w;
}
__device__ __forceinline__ void load4(const bf16* p, float* o) {
    const ushort4 v = *(const ushort4*)(const void*)p;
    o[0] = b2f(v.x); o[1] = b2f(v.y); o[2] = b2f(v.z); o[3] = b2f(v.w);
}

__device__ __forceinline__ float softplus_f(float x) {
    return (x > 20.f) ? x : log1pf(__expf(x));
}
__device__ __forceinline__ float silu_f(float x) {
    return x / (1.f + __expf(-x));
}

__device__ __forceinline__ void pack8(const float4 a, const float4 b, u16* dst) {
    u16 t[8] = {f2b(a.x), f2b(a.y), f2b(a.z), f2b(a.w),
                f2b(b.x), f2b(b.y), f2b(b.z), f2b(b.w)};
    *(u16x8*)dst = *(const u16x8*)t;
}

// ---------------- MFMA GEMM: C[m][n] = sum_k A[m][k] * W[n][k] ----------------
// 128x128 tile, BK=32. W always fp32 (cvt in staging).
// ASRC 0: A fp32.  ASRC 2: A bf16 y gated by silu(bf16 z) (Ag).
// EPI 0: bf16 store bd[t][col], GEMM rows r=l*B+b -> t=b*L+l  (in_proj halves)
// EPI 1: fp32 store out[l][b][col], GEMM rows t=b*L+l          (out_proj)
template <int ASRC, int EPI>
__global__ __launch_bounds__(256) void mgemm(
    const void* __restrict__ Aptr, const u16* __restrict__ Ag, int lda,
    const float* __restrict__ W, int ldb, int K,
    u16* __restrict__ bd, float* __restrict__ fout)
{
    __shared__ u16 As[128][40];   // stride 80B: 16B-aligned frags, 2-way read conflicts (free)
    __shared__ u16 Bs[128][40];

    const int tid = threadIdx.x;
    const int m0 = blockIdx.x * 128;
    const int n0 = blockIdx.y * 128;

    // staging coords: 2 threads per row, 16 k-elems each
    const int sr = tid >> 1;            // 0..127
    const int sh = (tid & 1) << 4;      // 0 or 16

    // wave coords
    const int w  = tid >> 6;
    const int wr = (w >> 1) << 6;       // m quadrant offset
    const int wc = (w & 1) << 6;        // n quadrant offset
    const int ln = tid & 63;
    const int lm = ln & 15;
    const int q8 = (ln >> 4) << 3;      // k-offset of frag (quad*8)

    f32x4 acc[4][4] = {};

    for (int k0 = 0; k0 < K; k0 += 32) {
        // ---- stage A ----
        u16 ta[16];
        if (ASRC == 0) {
            const float* ap = (const float*)Aptr + (size_t)(m0 + sr) * lda + k0 + sh;
            float4 v0 = *(const float4*)ap;
            float4 v1 = *(const float4*)(ap + 4);
            float4 v2 = *(const float4*)(ap + 8);
            float4 v3 = *(const float4*)(ap + 12);
            pack8(v0, v1, ta);
            pack8(v2, v3, ta + 8);
        } else {
            const size_t off = (size_t)(m0 + sr) * lda + k0 + sh;
            const u16x8 y0 = *(const u16x8*)((const u16*)Aptr + off);
            const u16x8 y1 = *(const u16x8*)((const u16*)Aptr + off + 8);
            const u16x8 z0 = *(const u16x8*)(Ag + off);
            const u16x8 z1 = *(const u16x8*)(Ag + off + 8);
#pragma unroll
            for (int j = 0; j < 8; ++j) {
                ta[j]     = f2b(b2f(y0[j]) * silu_f(b2f(z0[j])));
                ta[j + 8] = f2b(b2f(y1[j]) * silu_f(b2f(z1[j])));
            }
        }
        // ---- stage W ----
        u16 tb[16];
        {
            const float* wp = W + (size_t)(n0 + sr) * ldb + k0 + sh;
            float4 v0 = *(const float4*)wp;
            float4 v1 = *(const float4*)(wp + 4);
            float4 v2 = *(const float4*)(wp + 8);
            float4 v3 = *(const float4*)(wp + 12);
            pack8(v0, v1, tb);
            pack8(v2, v3, tb + 8);
        }

        if (k0) __syncthreads();
        *(u16x8*)&As[sr][sh]     = *(const u16x8*)ta;
        *(u16x8*)&As[sr][sh + 8] = *(const u16x8*)(ta + 8);
        *(u16x8*)&Bs[sr][sh]     = *(const u16x8*)tb;
        *(u16x8*)&Bs[sr][sh + 8] = *(const u16x8*)(tb + 8);
        __syncthreads();

        bf16x8 af[4], bf[4];
#pragma unroll
        for (int i = 0; i < 4; ++i)
            af[i] = *(const bf16x8*)&As[wr + i * 16 + lm][q8];
#pragma unroll
        for (int j = 0; j < 4; ++j)
            bf[j] = *(const bf16x8*)&Bs[wc + j * 16 + lm][q8];
#pragma unroll
        for (int i = 0; i < 4; ++i)
#pragma unroll
            for (int j = 0; j < 4; ++j)
                acc[i][j] = __builtin_amdgcn_mfma_f32_16x16x32_bf16(
                    af[i], bf[j], acc[i][j], 0, 0, 0);
    }

    // ---- epilogue ----  C/D: col = lane&15, row = quad*4 + reg
    const int qr = (ln >> 4) << 2;
#pragma unroll
    for (int i = 0; i < 4; ++i) {
#pragma unroll
        for (int reg = 0; reg < 4; ++reg) {
            const int rg = m0 + wr + i * 16 + qr + reg;   // GEMM row
            if (EPI == 0) {
                const int bb = rg & (N_B - 1);            // r = l*B + b
                const int l = rg >> 1;
                const size_t t = (size_t)bb * L_SEQ + l;
#pragma unroll
                for (int j = 0; j < 4; ++j) {
                    const int c = n0 + wc + j * 16 + lm;
                    bd[t * D_I + c] = f2b(acc[i][j][reg]);
                }
            } else {
                const int bb = rg >> 11;                  // rg = t = b*L + l
                const int l = rg & (L_SEQ - 1);
                const size_t o = ((size_t)l * N_B + bb) * D_M;
#pragma unroll
                for (int j = 0; j < 4; ++j) {
                    const int c = n0 + wc + j * 16 + lm;
                    fout[o + c] = acc[i][j][reg];
                }
            }
        }
    }
}

// ---------------- small VALU GEMM (x_proj / dt) ----------------
// EPI 1: fp32 split96 -> f0 dtlr / f1 Bm / f2 Cm   (x_proj)
// EPI 2: softplus(acc + bias[col]) -> bf16 bd      (dt)
template <typename TA, int EPI>
__global__ __launch_bounds__(256) void gemm_k(
    const TA* __restrict__ A, int lda,
    const float* __restrict__ W, int ldb,
    int N, int K,
    float* __restrict__ f0, float* __restrict__ f1, float* __restrict__ f2,
    bf16* __restrict__ bd, const float* __restrict__ bias)
{
    __shared__ __align__(16) float As[16][68];
    __shared__ __align__(16) float Bs[16][68];

    const int tid = threadIdx.x;
    const int m0 = blockIdx.x * 64;
    const int n0 = blockIdx.y * 64;
    const int tx = tid & 15, ty = tid >> 4;
    const int lm = tid >> 2;
    const int lk = (tid & 3) << 2;

    float acc[4][4] = {};

    for (int k0 = 0; k0 < K; k0 += 16) {
        float av[4];
        float bv[4] = {0.f, 0.f, 0.f, 0.f};
        load4(A + (size_t)(m0 + lm) * lda + k0 + lk, av);
        const int nb = n0 + lm;
        if (nb < N) load4(W + (size_t)nb * ldb + k0 + lk, bv);

        if (k0) __syncthreads();
#pragma unroll
        for (int j = 0; j < 4; ++j) As[lk + j][lm] = av[j];
#pragma unroll
        for (int j = 0; j < 4; ++j) Bs[lk + j][lm] = bv[j];
        __syncthreads();

#pragma unroll
        for (int kk = 0; kk < 16; ++kk) {
            const float4 a4 = *(const float4*)&As[kk][ty << 2];
            const float4 b4 = *(const float4*)&Bs[kk][tx << 2];
            const float aa[4] = {a4.x, a4.y, a4.z, a4.w};
            const float bb[4] = {b4.x, b4.y, b4.z, b4.w};
#pragma unroll
            for (int i = 0; i < 4; ++i)
#pragma unroll
                for (int j = 0; j < 4; ++j)
                    acc[i][j] = fmaf(aa[i], bb[j], acc[i][j]);
        }
    }

    if (EPI == 1) {
#pragma unroll
        for (int i = 0; i < 4; ++i) {
            const size_t t = (size_t)(m0 + (ty << 2) + i);
#pragma unroll
            for (int j = 0; j < 4; ++j) {
                const int c = n0 + (tx << 2) + j;
                if (c >= 96) continue;
                const float v = acc[i][j];
                if (c < 64)      f0[t * 64 + c] = v;
                else if (c < 80) f1[t * 16 + (c - 64)] = v;
                else             f2[t * 16 + (c - 80)] = v;
            }
        }
    } else {
        float bvals[4];
        load4(bias + n0 + (tx << 2), bvals);
#pragma unroll
        for (int i = 0; i < 4; ++i) {
            const size_t t = (size_t)(m0 + (ty << 2) + i);
            const ushort4 v = make_ushort4(f2b(softplus_f(acc[i][0] + bvals[0])),
                                           f2b(softplus_f(acc[i][1] + bvals[1])),
                                           f2b(softplus_f(acc[i][2] + bvals[2])),
                                           f2b(softplus_f(acc[i][3] + bvals[3])));
            *(ushort4*)(void*)(bd + t * D_I + n0 + (tx << 2)) = v;
        }
    }
}

// ---------------- conv ----------------
__global__ __launch_bounds__(256) void conv_k(
    const bf16* __restrict__ x, const float* __restrict__ cw,
    const float* __restrict__ cb, bf16* __restrict__ xc)
{
    const int t = blockIdx.x;
    const int l = t & (L_SEQ - 1);
#pragma unroll
    for (int it = 0; it < 2; ++it) {
        const int d = ((int)threadIdx.x + it * 256) << 2;
        float w[4][4], bias[4], acc[4];
#pragma unroll
        for (int dd = 0; dd < 4; ++dd)
            load4(cw + (size_t)(d + dd) * 4, w[dd]);
        load4(cb + d, bias);
#pragma unroll
        for (int dd = 0; dd < 4; ++dd) acc[dd] = bias[dd];
#pragma unroll
        for (int j = 0; j < 4; ++j) {
            const int ll = l - 3 + j;
            if (ll >= 0) {
                float xv[4];
                load4(x + (size_t)(t - 3 + j) * D_I + d, xv);
#pragma unroll
                for (int dd = 0; dd < 4; ++dd)
                    acc[dd] = fmaf(xv[dd], w[dd][j], acc[dd]);
            }
        }
        const ushort4 v = make_ushort4(f2b(silu_f(acc[0])), f2b(silu_f(acc[1])),
                                       f2b(silu_f(acc[2])), f2b(silu_f(acc[3])));
        *(ushort4*)(void*)(xc + (size_t)t * D_I + d) = v;
    }
}

// ---------------- chunked scan ----------------
template <int PHASE>
__global__ __launch_bounds__(256) void scan_chunk(
    bf16* __restrict__ dy, const bf16* __restrict__ u,
    const float* __restrict__ Bm, const float* __restrict__ Cm,
    const float* __restrict__ Alog, const float* __restrict__ Dp,
    float* __restrict__ Pc, float* __restrict__ Qc,
    const float* __restrict__ Sin)
{
    __shared__ float dl_s[CT][16];
    __shared__ float u_s[CT][16];
    __shared__ float b_s[CT][16];
    __shared__ float c_s[CT][16];

    const int tid = threadIdx.x;
    const int d0 = blockIdx.x * 16;
    const int b  = blockIdx.y;
    const int c  = blockIdx.z;
    const int row0 = b * L_SEQ + c * CT;

    for (int e = tid; e < CT * 16; e += 256) {
        const int l = e >> 4, j = e & 15;
        dl_s[l][j] = __bfloat162float(dy[(size_t)(row0 + l) * D_I + d0 + j]);
        u_s[l][j]  = __bfloat162float(u [(size_t)(row0 + l) * D_I + d0 + j]);
        ((float*)b_s)[e] = Bm[(size_t)row0 * D_ST + e];
        if (PHASE == 1)
            ((float*)c_s)[e] = Cm[(size_t)row0 * D_ST + e];
    }
    __syncthreads();

    const int n  = tid & 15;
    const int dl = tid >> 4;
    const int d  = d0 + dl;
    const float Av = -__expf(Alog[(size_t)d * D_ST + n]);
    const size_t pqi = (((size_t)b * CHNK + c) * D_I + d) * D_ST + n;

    float s = (PHASE == 1) ? Sin[pqi] : 0.f;
    float P = 1.f;
    const float Dd = (PHASE == 1) ? Dp[d] : 0.f;

#pragma unroll 4
    for (int l = 0; l < CT; ++l) {
        const float dv = dl_s[l][dl];
        const float uv = u_s[l][dl];
        const float bn = b_s[l][n];
        const float dA = __expf(dv * Av);
        if (PHASE == 0) P *= dA;
        s = fmaf(s, dA, dv * uv * bn);
        if (PHASE == 1) {
            float contrib = s * c_s[l][n];
            contrib += __shfl_xor(contrib, 1);
            contrib += __shfl_xor(contrib, 2);
            contrib += __shfl_xor(contrib, 4);
            contrib += __shfl_xor(contrib, 8);
            if (n == 0)
                dy[(size_t)(row0 + l) * D_I + d] = __float2bfloat16(contrib + uv * Dd);
        }
    }

    if (PHASE == 0) {
        Pc[pqi] = P;
        Qc[pqi] = s;
    }
}

__global__ __launch_bounds__(256) void scan_comb(
    const float* __restrict__ Pc, const float* __restrict__ Qc,
    float* __restrict__ Sin)
{
    const int b = blockIdx.y;
    const int d = blockIdx.x * 16 + (threadIdx.x >> 4);
    const int n = threadIdx.x & 15;
    float s = 0.f;
#pragma unroll
    for (int c = 0; c < CHNK; ++c) {
        const size_t idx = (((size_t)b * CHNK + c) * D_I + d) * D_ST + n;
        Sin[idx] = s;
        s = fmaf(s, Pc[idx], Qc[idx]);
    }
}

__global__ void zfill(float* o) {
    o[(size_t)blockIdx.x * 256 + threadIdx.x] = 0.f;
}

extern "C" void kernel_launch(void* const* d_in, const int* in_sizes, int n_in,
                              void* d_out, int out_size, void* d_ws, size_t ws_size,
                              hipStream_t stream)
{
    const float* hs   = (const float*)d_in[0];
    const float* Win  = (const float*)d_in[1];
    const float* cw   = (const float*)d_in[2];
    const float* cb   = (const float*)d_in[3];
    const float* Wx   = (const float*)d_in[4];
    const float* Wdt  = (const float*)d_in[5];
    const float* dtb  = (const float*)d_in[6];
    const float* Alog = (const float*)d_in[7];
    const float* Dp   = (const float*)d_in[8];
    const float* Wout = (const float*)d_in[9];
    float* out = (float*)d_out;

    const size_t SZ = (size_t)N_B * L_SEQ * D_I;        // 8,388,608
    const size_t NT = (size_t)N_B * L_SEQ;              // 4096 tokens
    const size_t NEED = SZ * 2 * sizeof(bf16)
                      + NT * (R_DT + 2 * D_ST) * sizeof(float);   // 35.1 MB
    if (ws_size < NEED) {
        zfill<<<dim3((unsigned)((size_t)out_size / 256)), 256, 0, stream>>>(out);
        return;
    }

    bf16* RA = (bf16*)d_ws;            // x -> delta -> y
    bf16* RB = RA + SZ;                // u -> z
    float* dtlr = (float*)(RB + SZ);   // [4096][64]
    float* Bm   = dtlr + NT * R_DT;    // [4096][16]
    float* Cm   = Bm + NT * D_ST;      // [4096][16]
    const size_t PQ = (size_t)N_B * CHNK * D_I * D_ST;  // 4 MB each
    float* Pc  = out;                  // scan scratch in d_out (dead until step 7)
    float* Qc  = Pc + PQ;
    float* Sin = Qc + PQ;

    // 1) in_proj x-half: x = hs @ W_in[0:D_I]^T -> RA  (MFMA)
    mgemm<0, 0><<<dim3(32, 16), 256, 0, stream>>>(
        hs, nullptr, D_M, Win, D_M, D_M, (u16*)RA, nullptr);
    // 2) conv + silu: RA(x) -> RB(u)
    conv_k<<<dim3(N_B * L_SEQ), 256, 0, stream>>>(RA, cw, cb, RB);
    // 3) x_proj -> dtlr/Bm/Cm (VALU)
    gemm_k<bf16, 1><<<dim3(64, 2), 256, 0, stream>>>(
        RB, D_I, Wx, D_I, 96, D_I, dtlr, Bm, Cm, nullptr, nullptr);
    // 4) dt -> delta (RA, over dead x) (VALU)
    gemm_k<float, 2><<<dim3(64, 32), 256, 0, stream>>>(
        dtlr, R_DT, Wdt, R_DT, D_I, R_DT, nullptr, nullptr, nullptr, RA, dtb);
    // 5) chunked scan: P,Q -> prefix -> replay (y over delta in RA)
    scan_chunk<0><<<dim3(D_I / 16, N_B, CHNK), 256, 0, stream>>>(
        RA, RB, Bm, Cm, Alog, Dp, Pc, Qc, nullptr);
    scan_comb<<<dim3(D_I / 16, N_B), 256, 0, stream>>>(Pc, Qc, Sin);
    scan_chunk<1><<<dim3(D_I / 16, N_B, CHNK), 256, 0, stream>>>(
        RA, RB, Bm, Cm, Alog, Dp, nullptr, nullptr, Sin);
    // 6) in_proj z-half: z = hs @ W_in[D_I:]^T -> RB (over dead u)  (MFMA)
    mgemm<0, 0><<<dim3(32, 16), 256, 0, stream>>>(
        hs, nullptr, D_M, Win + (size_t)D_I * D_M, D_M, D_M, (u16*)RB, nullptr);
    // 7) out_proj, gated: out = (y * silu(z)) @ W_out^T  (MFMA)
    mgemm<2, 1><<<dim3(32, 8), 256, 0, stream>>>(
        RA, (const u16*)RB, D_I, Wout, D_I, D_I, nullptr, out);
}

// Round 8
// 543.615 us; speedup vs baseline: 4.1432x; 1.1966x over previous
//
#include <hip/hip_runtime.h>
#include <hip/hip_bf16.h>

// Mamba block forward, MI355X. Round 8: register-state chunked scan.
// Round-7: scan_chunk 2x151us = 46% of 650us, latency-bound on a 4-deep
// ds_swizzle reduction chain (~177 cyc/wave-iter for ~30 cyc of VALU).
// New layout: lane quad = one d-channel, 4 states per lane in registers;
// reduction = 2 quad shfl_xor (DPP, VALU-rate); B/C in LDS; depth-2
// software pipeline on delta/u loads. 1024 blocks, 16 waves/CU.
// L=2048, B=2, D_MODEL=1024, D_INNER=2048, D_STATE=16, DT_RANK=64, D_CONV=4.

#define L_SEQ 2048
#define N_B   2
#define D_M   1024
#define D_I   2048
#define D_ST  16
#define R_DT  64
#define CHNK  16
#define CT    128

using bf16 = __hip_bfloat16;
typedef unsigned short u16;
typedef u16 u16x8 __attribute__((ext_vector_type(8)));
typedef __bf16 bf16x8 __attribute__((ext_vector_type(8)));
typedef float f32x4 __attribute__((ext_vector_type(4)));

__device__ __forceinline__ float b2f(u16 u) {
    union { unsigned int i; float f; } x;
    x.i = ((unsigned int)u) << 16;
    return x.f;
}
__device__ __forceinline__ u16 f2b(float f) {
    union { bf16 h; u16 s; } x;
    x.h = __float2bfloat16(f);
    return x.s;
}

__device__ __forceinline__ void load4(const float* p, float* o) {
    const float4 v = *(const float4*)p;
    o[0] = v.x; o[1] = v.y; o[2] = v.z; o[3] = v.w;
}
__device__ __forceinline__ void load4(const bf16* p, float* o) {
    const ushort4 v = *(const ushort4*)(const void*)p;
    o[0] = b2f(v.x); o[1] = b2f(v.y); o[2] = b2f(v.z); o[3] = b2f(v.w);
}

__device__ __forceinline__ float softplus_f(float x) {
    return (x > 20.f) ? x : log1pf(__expf(x));
}
__device__ __forceinline__ float silu_f(float x) {
    return x / (1.f + __expf(-x));
}

__device__ __forceinline__ void pack8(const float4 a, const float4 b, u16* dst) {
    u16 t[8] = {f2b(a.x), f2b(a.y), f2b(a.z), f2b(a.w),
                f2b(b.x), f2b(b.y), f2b(b.z), f2b(b.w)};
    *(u16x8*)dst = *(const u16x8*)t;
}

// ---------------- MFMA GEMM (unchanged from round 7) ----------------
template <int ASRC, int EPI>
__global__ __launch_bounds__(256) void mgemm(
    const void* __restrict__ Aptr, const u16* __restrict__ Ag, int lda,
    const float* __restrict__ W, int ldb, int K,
    u16* __restrict__ bd, float* __restrict__ fout)
{
    __shared__ u16 As[128][40];
    __shared__ u16 Bs[128][40];

    const int tid = threadIdx.x;
    const int m0 = blockIdx.x * 128;
    const int n0 = blockIdx.y * 128;

    const int sr = tid >> 1;
    const int sh = (tid & 1) << 4;

    const int w  = tid >> 6;
    const int wr = (w >> 1) << 6;
    const int wc = (w & 1) << 6;
    const int ln = tid & 63;
    const int lm = ln & 15;
    const int q8 = (ln >> 4) << 3;

    f32x4 acc[4][4] = {};

    for (int k0 = 0; k0 < K; k0 += 32) {
        u16 ta[16];
        if (ASRC == 0) {
            const float* ap = (const float*)Aptr + (size_t)(m0 + sr) * lda + k0 + sh;
            float4 v0 = *(const float4*)ap;
            float4 v1 = *(const float4*)(ap + 4);
            float4 v2 = *(const float4*)(ap + 8);
            float4 v3 = *(const float4*)(ap + 12);
            pack8(v0, v1, ta);
            pack8(v2, v3, ta + 8);
        } else {
            const size_t off = (size_t)(m0 + sr) * lda + k0 + sh;
            const u16x8 y0 = *(const u16x8*)((const u16*)Aptr + off);
            const u16x8 y1 = *(const u16x8*)((const u16*)Aptr + off + 8);
            const u16x8 z0 = *(const u16x8*)(Ag + off);
            const u16x8 z1 = *(const u16x8*)(Ag + off + 8);
#pragma unroll
            for (int j = 0; j < 8; ++j) {
                ta[j]     = f2b(b2f(y0[j]) * silu_f(b2f(z0[j])));
                ta[j + 8] = f2b(b2f(y1[j]) * silu_f(b2f(z1[j])));
            }
        }
        u16 tb[16];
        {
            const float* wp = W + (size_t)(n0 + sr) * ldb + k0 + sh;
            float4 v0 = *(const float4*)wp;
            float4 v1 = *(const float4*)(wp + 4);
            float4 v2 = *(const float4*)(wp + 8);
            float4 v3 = *(const float4*)(wp + 12);
            pack8(v0, v1, tb);
            pack8(v2, v3, tb + 8);
        }

        if (k0) __syncthreads();
        *(u16x8*)&As[sr][sh]     = *(const u16x8*)ta;
        *(u16x8*)&As[sr][sh + 8] = *(const u16x8*)(ta + 8);
        *(u16x8*)&Bs[sr][sh]     = *(const u16x8*)tb;
        *(u16x8*)&Bs[sr][sh + 8] = *(const u16x8*)(tb + 8);
        __syncthreads();

        bf16x8 af[4], bf[4];
#pragma unroll
        for (int i = 0; i < 4; ++i)
            af[i] = *(const bf16x8*)&As[wr + i * 16 + lm][q8];
#pragma unroll
        for (int j = 0; j < 4; ++j)
            bf[j] = *(const bf16x8*)&Bs[wc + j * 16 + lm][q8];
#pragma unroll
        for (int i = 0; i < 4; ++i)
#pragma unroll
            for (int j = 0; j < 4; ++j)
                acc[i][j] = __builtin_amdgcn_mfma_f32_16x16x32_bf16(
                    af[i], bf[j], acc[i][j], 0, 0, 0);
    }

    const int qr = (ln >> 4) << 2;
#pragma unroll
    for (int i = 0; i < 4; ++i) {
#pragma unroll
        for (int reg = 0; reg < 4; ++reg) {
            const int rg = m0 + wr + i * 16 + qr + reg;
            if (EPI == 0) {
                const int bb = rg & (N_B - 1);
                const int l = rg >> 1;
                const size_t t = (size_t)bb * L_SEQ + l;
#pragma unroll
                for (int j = 0; j < 4; ++j) {
                    const int c = n0 + wc + j * 16 + lm;
                    bd[t * D_I + c] = f2b(acc[i][j][reg]);
                }
            } else {
                const int bb = rg >> 11;
                const int l = rg & (L_SEQ - 1);
                const size_t o = ((size_t)l * N_B + bb) * D_M;
#pragma unroll
                for (int j = 0; j < 4; ++j) {
                    const int c = n0 + wc + j * 16 + lm;
                    fout[o + c] = acc[i][j][reg];
                }
            }
        }
    }
}

// ---------------- small VALU GEMM (x_proj / dt) ----------------
template <typename TA, int EPI>
__global__ __launch_bounds__(256) void gemm_k(
    const TA* __restrict__ A, int lda,
    const float* __restrict__ W, int ldb,
    int N, int K,
    float* __restrict__ f0, float* __restrict__ f1, float* __restrict__ f2,
    bf16* __restrict__ bd, const float* __restrict__ bias)
{
    __shared__ __align__(16) float As[16][68];
    __shared__ __align__(16) float Bs[16][68];

    const int tid = threadIdx.x;
    const int m0 = blockIdx.x * 64;
    const int n0 = blockIdx.y * 64;
    const int tx = tid & 15, ty = tid >> 4;
    const int lm = tid >> 2;
    const int lk = (tid & 3) << 2;

    float acc[4][4] = {};

    for (int k0 = 0; k0 < K; k0 += 16) {
        float av[4];
        float bv[4] = {0.f, 0.f, 0.f, 0.f};
        load4(A + (size_t)(m0 + lm) * lda + k0 + lk, av);
        const int nb = n0 + lm;
        if (nb < N) load4(W + (size_t)nb * ldb + k0 + lk, bv);

        if (k0) __syncthreads();
#pragma unroll
        for (int j = 0; j < 4; ++j) As[lk + j][lm] = av[j];
#pragma unroll
        for (int j = 0; j < 4; ++j) Bs[lk + j][lm] = bv[j];
        __syncthreads();

#pragma unroll
        for (int kk = 0; kk < 16; ++kk) {
            const float4 a4 = *(const float4*)&As[kk][ty << 2];
            const float4 b4 = *(const float4*)&Bs[kk][tx << 2];
            const float aa[4] = {a4.x, a4.y, a4.z, a4.w};
            const float bb[4] = {b4.x, b4.y, b4.z, b4.w};
#pragma unroll
            for (int i = 0; i < 4; ++i)
#pragma unroll
                for (int j = 0; j < 4; ++j)
                    acc[i][j] = fmaf(aa[i], bb[j], acc[i][j]);
        }
    }

    if (EPI == 1) {
#pragma unroll
        for (int i = 0; i < 4; ++i) {
            const size_t t = (size_t)(m0 + (ty << 2) + i);
#pragma unroll
            for (int j = 0; j < 4; ++j) {
                const int c = n0 + (tx << 2) + j;
                if (c >= 96) continue;
                const float v = acc[i][j];
                if (c < 64)      f0[t * 64 + c] = v;
                else if (c < 80) f1[t * 16 + (c - 64)] = v;
                else             f2[t * 16 + (c - 80)] = v;
            }
        }
    } else {
        float bvals[4];
        load4(bias + n0 + (tx << 2), bvals);
#pragma unroll
        for (int i = 0; i < 4; ++i) {
            const size_t t = (size_t)(m0 + (ty << 2) + i);
            const ushort4 v = make_ushort4(f2b(softplus_f(acc[i][0] + bvals[0])),
                                           f2b(softplus_f(acc[i][1] + bvals[1])),
                                           f2b(softplus_f(acc[i][2] + bvals[2])),
                                           f2b(softplus_f(acc[i][3] + bvals[3])));
            *(ushort4*)(void*)(bd + t * D_I + n0 + (tx << 2)) = v;
        }
    }
}

// ---------------- conv ----------------
__global__ __launch_bounds__(256) void conv_k(
    const bf16* __restrict__ x, const float* __restrict__ cw,
    const float* __restrict__ cb, bf16* __restrict__ xc)
{
    const int t = blockIdx.x;
    const int l = t & (L_SEQ - 1);
#pragma unroll
    for (int it = 0; it < 2; ++it) {
        const int d = ((int)threadIdx.x + it * 256) << 2;
        float w[4][4], bias[4], acc[4];
#pragma unroll
        for (int dd = 0; dd < 4; ++dd)
            load4(cw + (size_t)(d + dd) * 4, w[dd]);
        load4(cb + d, bias);
#pragma unroll
        for (int dd = 0; dd < 4; ++dd) acc[dd] = bias[dd];
#pragma unroll
        for (int j = 0; j < 4; ++j) {
            const int ll = l - 3 + j;
            if (ll >= 0) {
                float xv[4];
                load4(x + (size_t)(t - 3 + j) * D_I + d, xv);
#pragma unroll
                for (int dd = 0; dd < 4; ++dd)
                    acc[dd] = fmaf(xv[dd], w[dd][j], acc[dd]);
            }
        }
        const ushort4 v = make_ushort4(f2b(silu_f(acc[0])), f2b(silu_f(acc[1])),
                                       f2b(silu_f(acc[2])), f2b(silu_f(acc[3])));
        *(ushort4*)(void*)(xc + (size_t)t * D_I + d) = v;
    }
}

// ---------------- chunked scan, register-state version ----------------
// Block 256 = 4 waves; lane quad = one d channel; lane holds 4 states
// (n = (tid&3)*4+j). Grid (D_I/64, B, CHNK) = 1024 blocks.
// PHASE 0: P=prod(dA), Q=chunk scan from 0 -> Pc/Qc (float4, coalesced).
// PHASE 1: s from Sin; y = sum_n s*C (2 quad shfl_xor) + u*D; y written
// in place over delta (thread-local read-then-write, depth-2 prefetch).
template <int PHASE>
__global__ __launch_bounds__(256) void scan_chunk(
    bf16* __restrict__ dy, const bf16* __restrict__ u,
    const float* __restrict__ Bm, const float* __restrict__ Cm,
    const float* __restrict__ Alog, const float* __restrict__ Dp,
    float* __restrict__ Pc, float* __restrict__ Qc,
    const float* __restrict__ Sin)
{
    __shared__ float Bs[CT][D_ST];
    __shared__ float Cs[(PHASE == 1) ? CT : 1][D_ST];

    const int tid = threadIdx.x;
    const int b  = blockIdx.y;
    const int c  = blockIdx.z;
    const int row0 = b * L_SEQ + c * CT;

    {   // stage B (and C) chunk: 2048 floats each, float4-coalesced
        const float4* src = (const float4*)(Bm + (size_t)row0 * D_ST);
        float4* dst = (float4*)Bs;
        for (int e = tid; e < CT * D_ST / 4; e += 256) dst[e] = src[e];
        if (PHASE == 1) {
            const float4* s2 = (const float4*)(Cm + (size_t)row0 * D_ST);
            float4* d2 = (float4*)Cs;
            for (int e = tid; e < CT * D_ST / 4; e += 256) d2[e] = s2[e];
        }
    }
    __syncthreads();

    const int d  = blockIdx.x * 64 + (tid >> 2);
    const int ns = tid & 3;                       // states n = ns*4 .. ns*4+3
    const size_t pqbase = (((size_t)b * CHNK + c) * D_I + d) * D_ST + ns * 4;

    float Av[4];
    {
        const float4 a4 = *(const float4*)(Alog + (size_t)d * D_ST + ns * 4);
        Av[0] = -__expf(a4.x); Av[1] = -__expf(a4.y);
        Av[2] = -__expf(a4.z); Av[3] = -__expf(a4.w);
    }

    float st[4] = {0.f, 0.f, 0.f, 0.f};
    float P[4]  = {1.f, 1.f, 1.f, 1.f};
    if (PHASE == 1) {
        const float4 s0 = *(const float4*)(Sin + pqbase);
        st[0] = s0.x; st[1] = s0.y; st[2] = s0.z; st[3] = s0.w;
    }
    const float Dd = (PHASE == 1) ? Dp[d] : 0.f;

    const bf16* up = u + (size_t)row0 * D_I + d;
    bf16* dp = dy + (size_t)row0 * D_I + d;

    // depth-2 software pipeline on delta/u
    float dv0 = __bfloat162float(dp[0]);
    float uv0 = __bfloat162float(up[0]);
    float dv1 = __bfloat162float(dp[D_I]);
    float uv1 = __bfloat162float(up[D_I]);

    for (int l = 0; l < CT; ++l) {
        const int lp = (l + 2 < CT) ? (l + 2) : (CT - 1);
        const float dvn = __bfloat162float(dp[(size_t)lp * D_I]);
        const float uvn = __bfloat162float(up[(size_t)lp * D_I]);

        const float dv = dv0, uv = uv0;
        const float dvu = dv * uv;
        float bn[4], cn[4] = {0.f, 0.f, 0.f, 0.f};
        {
            const float4 b4 = *(const float4*)&Bs[l][ns * 4];
            bn[0] = b4.x; bn[1] = b4.y; bn[2] = b4.z; bn[3] = b4.w;
        }
        if (PHASE == 1) {
            const float4 c4 = *(const float4*)&Cs[l][ns * 4];
            cn[0] = c4.x; cn[1] = c4.y; cn[2] = c4.z; cn[3] = c4.w;
        }

        float y = 0.f;
#pragma unroll
        for (int j = 0; j < 4; ++j) {
            const float dA = __expf(dv * Av[j]);
            if (PHASE == 0) P[j] *= dA;
            st[j] = fmaf(st[j], dA, dvu * bn[j]);
            if (PHASE == 1) y = fmaf(st[j], cn[j], y);
        }
        if (PHASE == 1) {
            y += __shfl_xor(y, 1);      // quad-level: DPP, VALU-rate
            y += __shfl_xor(y, 2);
            if (ns == 0)
                dp[(size_t)l * D_I] = __float2bfloat16(y + uv * Dd);
        }
        dv0 = dv1; uv0 = uv1; dv1 = dvn; uv1 = uvn;
    }

    if (PHASE == 0) {
        *(float4*)(Pc + pqbase) = make_float4(P[0], P[1], P[2], P[3]);
        *(float4*)(Qc + pqbase) = make_float4(st[0], st[1], st[2], st[3]);
    }
}

// Prefix over chunks (unchanged)
__global__ __launch_bounds__(256) void scan_comb(
    const float* __restrict__ Pc, const float* __restrict__ Qc,
    float* __restrict__ Sin)
{
    const int b = blockIdx.y;
    const int d = blockIdx.x * 16 + (threadIdx.x >> 4);
    const int n = threadIdx.x & 15;
    float s = 0.f;
#pragma unroll
    for (int c = 0; c < CHNK; ++c) {
        const size_t idx = (((size_t)b * CHNK + c) * D_I + d) * D_ST + n;
        Sin[idx] = s;
        s = fmaf(s, Pc[idx], Qc[idx]);
    }
}

__global__ void zfill(float* o) {
    o[(size_t)blockIdx.x * 256 + threadIdx.x] = 0.f;
}

extern "C" void kernel_launch(void* const* d_in, const int* in_sizes, int n_in,
                              void* d_out, int out_size, void* d_ws, size_t ws_size,
                              hipStream_t stream)
{
    const float* hs   = (const float*)d_in[0];
    const float* Win  = (const float*)d_in[1];
    const float* cw   = (const float*)d_in[2];
    const float* cb   = (const float*)d_in[3];
    const float* Wx   = (const float*)d_in[4];
    const float* Wdt  = (const float*)d_in[5];
    const float* dtb  = (const float*)d_in[6];
    const float* Alog = (const float*)d_in[7];
    const float* Dp   = (const float*)d_in[8];
    const float* Wout = (const float*)d_in[9];
    float* out = (float*)d_out;

    const size_t SZ = (size_t)N_B * L_SEQ * D_I;        // 8,388,608
    const size_t NT = (size_t)N_B * L_SEQ;              // 4096 tokens
    const size_t NEED = SZ * 2 * sizeof(bf16)
                      + NT * (R_DT + 2 * D_ST) * sizeof(float);   // 35.1 MB
    if (ws_size < NEED) {
        zfill<<<dim3((unsigned)((size_t)out_size / 256)), 256, 0, stream>>>(out);
        return;
    }

    bf16* RA = (bf16*)d_ws;            // x -> delta -> y
    bf16* RB = RA + SZ;                // u -> z
    float* dtlr = (float*)(RB + SZ);   // [4096][64]
    float* Bm   = dtlr + NT * R_DT;    // [4096][16]
    float* Cm   = Bm + NT * D_ST;      // [4096][16]
    const size_t PQ = (size_t)N_B * CHNK * D_I * D_ST;  // 4 MB each
    float* Pc  = out;                  // scan scratch in d_out (dead until step 7)
    float* Qc  = Pc + PQ;
    float* Sin = Qc + PQ;

    // 1) in_proj x-half: x = hs @ W_in[0:D_I]^T -> RA  (MFMA)
    mgemm<0, 0><<<dim3(32, 16), 256, 0, stream>>>(
        hs, nullptr, D_M, Win, D_M, D_M, (u16*)RA, nullptr);
    // 2) conv + silu: RA(x) -> RB(u)
    conv_k<<<dim3(N_B * L_SEQ), 256, 0, stream>>>(RA, cw, cb, RB);
    // 3) x_proj -> dtlr/Bm/Cm (VALU)
    gemm_k<bf16, 1><<<dim3(64, 2), 256, 0, stream>>>(
        RB, D_I, Wx, D_I, 96, D_I, dtlr, Bm, Cm, nullptr, nullptr);
    // 4) dt -> delta (RA, over dead x) (VALU)
    gemm_k<float, 2><<<dim3(64, 32), 256, 0, stream>>>(
        dtlr, R_DT, Wdt, R_DT, D_I, R_DT, nullptr, nullptr, nullptr, RA, dtb);
    // 5) chunked scan: P,Q -> prefix -> replay (y over delta in RA)
    scan_chunk<0><<<dim3(D_I / 64, N_B, CHNK), 256, 0, stream>>>(
        RA, RB, Bm, Cm, Alog, Dp, Pc, Qc, nullptr);
    scan_comb<<<dim3(D_I / 16, N_B), 256, 0, stream>>>(Pc, Qc, Sin);
    scan_chunk<1><<<dim3(D_I / 64, N_B, CHNK), 256, 0, stream>>>(
        RA, RB, Bm, Cm, Alog, Dp, nullptr, nullptr, Sin);
    // 6) in_proj z-half: z = hs @ W_in[D_I:]^T -> RB (over dead u)  (MFMA)
    mgemm<0, 0><<<dim3(32, 16), 256, 0, stream>>>(
        hs, nullptr, D_M, Win + (size_t)D_I * D_M, D_M, D_M, (u16*)RB, nullptr);
    // 7) out_proj, gated: out = (y * silu(z)) @ W_out^T  (MFMA)
    mgemm<2, 1><<<dim3(32, 8), 256, 0, stream>>>(
        RA, (const u16*)RB, D_I, Wout, D_I, D_I, nullptr, out);
}

// Round 9
// 452.109 us; speedup vs baseline: 4.9817x; 1.2024x over previous
//
#include <hip/hip_runtime.h>
#include <hip/hip_bf16.h>

// Mamba block forward, MI355X. Round 9: async-staged bf16 MFMA GEMMs.
// Round-8: 3x mgemm ~127us = 70%, MfmaUtil 5% — fp32->bf16 cvt + VGPR round
// trip in the K-loop. Fix: one-time cvt of hs/Win/Wout to bf16 (ws), then
// m97-style bgemm: 128x128 tile, BK=32, global_load_lds width=16, XOR-swizzled
// LDS chunks (2-way conflicts only). Gating y*=silu(z) as elementwise pass.
// ws layout (53.7 MiB): RA | RB | bhs | bWin | bWout | dtlr/Bm/Cm.
// L=2048, B=2, D_MODEL=1024, D_INNER=2048, D_STATE=16, DT_RANK=64, D_CONV=4.

#define L_SEQ 2048
#define N_B   2
#define D_M   1024
#define D_I   2048
#define D_ST  16
#define R_DT  64
#define CHNK  16
#define CT    128

using bf16 = __hip_bfloat16;
typedef unsigned short u16;
typedef u16 u16x8 __attribute__((ext_vector_type(8)));
typedef __bf16 bf16x8 __attribute__((ext_vector_type(8)));
typedef float f32x4 __attribute__((ext_vector_type(4)));

__device__ __forceinline__ float b2f(u16 u) {
    union { unsigned int i; float f; } x;
    x.i = ((unsigned int)u) << 16;
    return x.f;
}
__device__ __forceinline__ u16 f2b(float f) {
    union { bf16 h; u16 s; } x;
    x.h = __float2bfloat16(f);
    return x.s;
}

__device__ __forceinline__ void load4(const float* p, float* o) {
    const float4 v = *(const float4*)p;
    o[0] = v.x; o[1] = v.y; o[2] = v.z; o[3] = v.w;
}
__device__ __forceinline__ void load4(const bf16* p, float* o) {
    const ushort4 v = *(const ushort4*)(const void*)p;
    o[0] = b2f(v.x); o[1] = b2f(v.y); o[2] = b2f(v.z); o[3] = b2f(v.w);
}

__device__ __forceinline__ float softplus_f(float x) {
    return (x > 20.f) ? x : log1pf(__expf(x));
}
__device__ __forceinline__ float silu_f(float x) {
    return x / (1.f + __expf(-x));
}

// async global->LDS, 16 B per lane; ldsdst is wave-uniform, HW adds lane*16.
__device__ __forceinline__ void gl_lds16(const u16* g, u16* l) {
    __builtin_amdgcn_global_load_lds(
        (const __attribute__((address_space(1))) void*)g,
        (__attribute__((address_space(3))) void*)l, 16, 0, 0);
}

// ---------------- async bf16 MFMA GEMM ----------------
// C[m][n] = sum_k A[m][k]*Wb[n][k], A/Wb bf16 row-major. 128x128 tile, BK=32.
// LDS row r holds its 4 8-elem chunks XOR-swizzled: global chunk q sits in
// slot (q + (r>>1)) & 3  => frag reads are 2-way-conflict (free), and
// global_load_lds's lane-consecutive LDS writes are satisfied exactly.
// EPI 0: bf16 store bd[t][col], rows r=l*B+b -> t=b*L+l   (in_proj halves)
// EPI 1: fp32 store out[l][b][col], rows t=b*L+l           (out_proj)
template <int EPI>
__global__ __launch_bounds__(256) void bgemm(
    const u16* __restrict__ A, int lda,
    const u16* __restrict__ Wb, int ldb, int K,
    u16* __restrict__ bd, float* __restrict__ fout)
{
    __shared__ u16 As[128 * 32];
    __shared__ u16 Bs[128 * 32];

    const int tid = threadIdx.x;
    const int m0 = blockIdx.x * 128;
    const int n0 = blockIdx.y * 128;
    const int w  = tid >> 6;
    const int ln = tid & 63;

    // staging: issue I covers rows I*64 + w*16 + ln/4; lane's LDS slot = ln&3
    const int sr0 = (w << 4) + (ln >> 2);
    const int sr1 = sr0 + 64;
    const int sx  = ln & 3;
    const int qa0 = (sx - (sr0 >> 1)) & 3;   // global chunk that fills slot sx
    const int qa1 = (sx - (sr1 >> 1)) & 3;

    const u16* ga0 = A  + (size_t)(m0 + sr0) * lda + qa0 * 8;
    const u16* ga1 = A  + (size_t)(m0 + sr1) * lda + qa1 * 8;
    const u16* gb0 = Wb + (size_t)(n0 + sr0) * ldb + qa0 * 8;
    const u16* gb1 = Wb + (size_t)(n0 + sr1) * ldb + qa1 * 8;
    u16* la0 = As + ((w << 4) + 0) * 32;     // wave-uniform LDS bases
    u16* la1 = As + ((w << 4) + 64) * 32;
    u16* lb0 = Bs + ((w << 4) + 0) * 32;
    u16* lb1 = Bs + ((w << 4) + 64) * 32;

    // fragment read offsets (u16 units)
    const int wr = (w >> 1) << 6;
    const int wc = (w & 1) << 6;
    const int lm = ln & 15;
    const int qf = ln >> 4;
    int aoff[4], boff[4];
#pragma unroll
    for (int i = 0; i < 4; ++i) {
        const int ra = wr + i * 16 + lm;
        aoff[i] = ra * 32 + (((qf + (ra >> 1)) & 3) << 3);
        const int rb = wc + i * 16 + lm;
        boff[i] = rb * 32 + (((qf + (rb >> 1)) & 3) << 3);
    }

    f32x4 acc[4][4] = {};

    for (int k0 = 0; k0 < K; k0 += 32) {
        if (k0) __syncthreads();
        gl_lds16(ga0 + k0, la0);
        gl_lds16(ga1 + k0, la1);
        gl_lds16(gb0 + k0, lb0);
        gl_lds16(gb1 + k0, lb1);
        __syncthreads();

        bf16x8 af[4], bf[4];
#pragma unroll
        for (int i = 0; i < 4; ++i) af[i] = *(const bf16x8*)&As[aoff[i]];
#pragma unroll
        for (int j = 0; j < 4; ++j) bf[j] = *(const bf16x8*)&Bs[boff[j]];
#pragma unroll
        for (int i = 0; i < 4; ++i)
#pragma unroll
            for (int j = 0; j < 4; ++j)
                acc[i][j] = __builtin_amdgcn_mfma_f32_16x16x32_bf16(
                    af[i], bf[j], acc[i][j], 0, 0, 0);
    }

    // epilogue: C/D col = lane&15, row = quad*4 + reg
    const int qr = (ln >> 4) << 2;
#pragma unroll
    for (int i = 0; i < 4; ++i) {
#pragma unroll
        for (int reg = 0; reg < 4; ++reg) {
            const int rg = m0 + wr + i * 16 + qr + reg;
            if (EPI == 0) {
                const int bb = rg & (N_B - 1);    // r = l*B + b
                const int l = rg >> 1;
                const size_t t = (size_t)bb * L_SEQ + l;
#pragma unroll
                for (int j = 0; j < 4; ++j)
                    bd[t * D_I + n0 + wc + j * 16 + lm] = f2b(acc[i][j][reg]);
            } else {
                const int bb = rg >> 11;          // rg = t = b*L + l
                const int l = rg & (L_SEQ - 1);
                const size_t o = ((size_t)l * N_B + bb) * D_M;
#pragma unroll
                for (int j = 0; j < 4; ++j)
                    fout[o + n0 + wc + j * 16 + lm] = acc[i][j][reg];
            }
        }
    }
}

// fp32 -> bf16 one-time conversion (8 elems/thread)
__global__ __launch_bounds__(256) void cvt_k(const float* __restrict__ s,
                                             u16* __restrict__ d)
{
    const size_t i = ((size_t)blockIdx.x * 256 + threadIdx.x) * 8;
    const float4 a = *(const float4*)(s + i);
    const float4 b = *(const float4*)(s + i + 4);
    u16 t[8] = {f2b(a.x), f2b(a.y), f2b(a.z), f2b(a.w),
                f2b(b.x), f2b(b.y), f2b(b.z), f2b(b.w)};
    *(u16x8*)(d + i) = *(const u16x8*)t;
}

// y *= silu(z), in place (8 elems/thread)
__global__ __launch_bounds__(256) void gate_k(u16* __restrict__ y,
                                              const u16* __restrict__ z)
{
    const size_t i = ((size_t)blockIdx.x * 256 + threadIdx.x) * 8;
    u16x8 yv = *(u16x8*)(y + i);
    const u16x8 zv = *(const u16x8*)(z + i);
    u16 t[8];
#pragma unroll
    for (int j = 0; j < 8; ++j)
        t[j] = f2b(b2f(yv[j]) * silu_f(b2f(zv[j])));
    *(u16x8*)(y + i) = *(const u16x8*)t;
}

// ---------------- small VALU GEMM (x_proj / dt) ----------------
template <typename TA, int EPI>
__global__ __launch_bounds__(256) void gemm_k(
    const TA* __restrict__ A, int lda,
    const float* __restrict__ W, int ldb,
    int N, int K,
    float* __restrict__ f0, float* __restrict__ f1, float* __restrict__ f2,
    bf16* __restrict__ bd, const float* __restrict__ bias)
{
    __shared__ __align__(16) float As[16][68];
    __shared__ __align__(16) float Bs[16][68];

    const int tid = threadIdx.x;
    const int m0 = blockIdx.x * 64;
    const int n0 = blockIdx.y * 64;
    const int tx = tid & 15, ty = tid >> 4;
    const int lm = tid >> 2;
    const int lk = (tid & 3) << 2;

    float acc[4][4] = {};

    for (int k0 = 0; k0 < K; k0 += 16) {
        float av[4];
        float bv[4] = {0.f, 0.f, 0.f, 0.f};
        load4(A + (size_t)(m0 + lm) * lda + k0 + lk, av);
        const int nb = n0 + lm;
        if (nb < N) load4(W + (size_t)nb * ldb + k0 + lk, bv);

        if (k0) __syncthreads();
#pragma unroll
        for (int j = 0; j < 4; ++j) As[lk + j][lm] = av[j];
#pragma unroll
        for (int j = 0; j < 4; ++j) Bs[lk + j][lm] = bv[j];
        __syncthreads();

#pragma unroll
        for (int kk = 0; kk < 16; ++kk) {
            const float4 a4 = *(const float4*)&As[kk][ty << 2];
            const float4 b4 = *(const float4*)&Bs[kk][tx << 2];
            const float aa[4] = {a4.x, a4.y, a4.z, a4.w};
            const float bb[4] = {b4.x, b4.y, b4.z, b4.w};
#pragma unroll
            for (int i = 0; i < 4; ++i)
#pragma unroll
                for (int j = 0; j < 4; ++j)
                    acc[i][j] = fmaf(aa[i], bb[j], acc[i][j]);
        }
    }

    if (EPI == 1) {
#pragma unroll
        for (int i = 0; i < 4; ++i) {
            const size_t t = (size_t)(m0 + (ty << 2) + i);
#pragma unroll
            for (int j = 0; j < 4; ++j) {
                const int c = n0 + (tx << 2) + j;
                if (c >= 96) continue;
                const float v = acc[i][j];
                if (c < 64)      f0[t * 64 + c] = v;
                else if (c < 80) f1[t * 16 + (c - 64)] = v;
                else             f2[t * 16 + (c - 80)] = v;
            }
        }
    } else {
        float bvals[4];
        load4(bias + n0 + (tx << 2), bvals);
#pragma unroll
        for (int i = 0; i < 4; ++i) {
            const size_t t = (size_t)(m0 + (ty << 2) + i);
            const ushort4 v = make_ushort4(f2b(softplus_f(acc[i][0] + bvals[0])),
                                           f2b(softplus_f(acc[i][1] + bvals[1])),
                                           f2b(softplus_f(acc[i][2] + bvals[2])),
                                           f2b(softplus_f(acc[i][3] + bvals[3])));
            *(ushort4*)(void*)(bd + t * D_I + n0 + (tx << 2)) = v;
        }
    }
}

// ---------------- conv ----------------
__global__ __launch_bounds__(256) void conv_k(
    const bf16* __restrict__ x, const float* __restrict__ cw,
    const float* __restrict__ cb, bf16* __restrict__ xc)
{
    const int t = blockIdx.x;
    const int l = t & (L_SEQ - 1);
#pragma unroll
    for (int it = 0; it < 2; ++it) {
        const int d = ((int)threadIdx.x + it * 256) << 2;
        float w[4][4], bias[4], acc[4];
#pragma unroll
        for (int dd = 0; dd < 4; ++dd)
            load4(cw + (size_t)(d + dd) * 4, w[dd]);
        load4(cb + d, bias);
#pragma unroll
        for (int dd = 0; dd < 4; ++dd) acc[dd] = bias[dd];
#pragma unroll
        for (int j = 0; j < 4; ++j) {
            const int ll = l - 3 + j;
            if (ll >= 0) {
                float xv[4];
                load4(x + (size_t)(t - 3 + j) * D_I + d, xv);
#pragma unroll
                for (int dd = 0; dd < 4; ++dd)
                    acc[dd] = fmaf(xv[dd], w[dd][j], acc[dd]);
            }
        }
        const ushort4 v = make_ushort4(f2b(silu_f(acc[0])), f2b(silu_f(acc[1])),
                                       f2b(silu_f(acc[2])), f2b(silu_f(acc[3])));
        *(ushort4*)(void*)(xc + (size_t)t * D_I + d) = v;
    }
}

// ---------------- chunked scan (round-8 register-state version) ----------------
template <int PHASE>
__global__ __launch_bounds__(256) void scan_chunk(
    bf16* __restrict__ dy, const bf16* __restrict__ u,
    const float* __restrict__ Bm, const float* __restrict__ Cm,
    const float* __restrict__ Alog, const float* __restrict__ Dp,
    float* __restrict__ Pc, float* __restrict__ Qc,
    const float* __restrict__ Sin)
{
    __shared__ float Bs[CT][D_ST];
    __shared__ float Cs[(PHASE == 1) ? CT : 1][D_ST];

    const int tid = threadIdx.x;
    const int b  = blockIdx.y;
    const int c  = blockIdx.z;
    const int row0 = b * L_SEQ + c * CT;

    {
        const float4* src = (const float4*)(Bm + (size_t)row0 * D_ST);
        float4* dst = (float4*)Bs;
        for (int e = tid; e < CT * D_ST / 4; e += 256) dst[e] = src[e];
        if (PHASE == 1) {
            const float4* s2 = (const float4*)(Cm + (size_t)row0 * D_ST);
            float4* d2 = (float4*)Cs;
            for (int e = tid; e < CT * D_ST / 4; e += 256) d2[e] = s2[e];
        }
    }
    __syncthreads();

    const int d  = blockIdx.x * 64 + (tid >> 2);
    const int ns = tid & 3;
    const size_t pqbase = (((size_t)b * CHNK + c) * D_I + d) * D_ST + ns * 4;

    float Av[4];
    {
        const float4 a4 = *(const float4*)(Alog + (size_t)d * D_ST + ns * 4);
        Av[0] = -__expf(a4.x); Av[1] = -__expf(a4.y);
        Av[2] = -__expf(a4.z); Av[3] = -__expf(a4.w);
    }

    float st[4] = {0.f, 0.f, 0.f, 0.f};
    float P[4]  = {1.f, 1.f, 1.f, 1.f};
    if (PHASE == 1) {
        const float4 s0 = *(const float4*)(Sin + pqbase);
        st[0] = s0.x; st[1] = s0.y; st[2] = s0.z; st[3] = s0.w;
    }
    const float Dd = (PHASE == 1) ? Dp[d] : 0.f;

    const bf16* up = u + (size_t)row0 * D_I + d;
    bf16* dp = dy + (size_t)row0 * D_I + d;

    float dv0 = __bfloat162float(dp[0]);
    float uv0 = __bfloat162float(up[0]);
    float dv1 = __bfloat162float(dp[D_I]);
    float uv1 = __bfloat162float(up[D_I]);

    for (int l = 0; l < CT; ++l) {
        const int lp = (l + 2 < CT) ? (l + 2) : (CT - 1);
        const float dvn = __bfloat162float(dp[(size_t)lp * D_I]);
        const float uvn = __bfloat162float(up[(size_t)lp * D_I]);

        const float dv = dv0, uv = uv0;
        const float dvu = dv * uv;
        float bn[4], cn[4] = {0.f, 0.f, 0.f, 0.f};
        {
            const float4 b4 = *(const float4*)&Bs[l][ns * 4];
            bn[0] = b4.x; bn[1] = b4.y; bn[2] = b4.z; bn[3] = b4.w;
        }
        if (PHASE == 1) {
            const float4 c4 = *(const float4*)&Cs[l][ns * 4];
            cn[0] = c4.x; cn[1] = c4.y; cn[2] = c4.z; cn[3] = c4.w;
        }

        float y = 0.f;
#pragma unroll
        for (int j = 0; j < 4; ++j) {
            const float dA = __expf(dv * Av[j]);
            if (PHASE == 0) P[j] *= dA;
            st[j] = fmaf(st[j], dA, dvu * bn[j]);
            if (PHASE == 1) y = fmaf(st[j], cn[j], y);
        }
        if (PHASE == 1) {
            y += __shfl_xor(y, 1);
            y += __shfl_xor(y, 2);
            if (ns == 0)
                dp[(size_t)l * D_I] = __float2bfloat16(y + uv * Dd);
        }
        dv0 = dv1; uv0 = uv1; dv1 = dvn; uv1 = uvn;
    }

    if (PHASE == 0) {
        *(float4*)(Pc + pqbase) = make_float4(P[0], P[1], P[2], P[3]);
        *(float4*)(Qc + pqbase) = make_float4(st[0], st[1], st[2], st[3]);
    }
}

__global__ __launch_bounds__(256) void scan_comb(
    const float* __restrict__ Pc, const float* __restrict__ Qc,
    float* __restrict__ Sin)
{
    const int b = blockIdx.y;
    const int d = blockIdx.x * 16 + (threadIdx.x >> 4);
    const int n = threadIdx.x & 15;
    float s = 0.f;
#pragma unroll
    for (int c = 0; c < CHNK; ++c) {
        const size_t idx = (((size_t)b * CHNK + c) * D_I + d) * D_ST + n;
        Sin[idx] = s;
        s = fmaf(s, Pc[idx], Qc[idx]);
    }
}

__global__ void zfill(float* o) {
    o[(size_t)blockIdx.x * 256 + threadIdx.x] = 0.f;
}

extern "C" void kernel_launch(void* const* d_in, const int* in_sizes, int n_in,
                              void* d_out, int out_size, void* d_ws, size_t ws_size,
                              hipStream_t stream)
{
    const float* hs   = (const float*)d_in[0];
    const float* Win  = (const float*)d_in[1];
    const float* cw   = (const float*)d_in[2];
    const float* cb   = (const float*)d_in[3];
    const float* Wx   = (const float*)d_in[4];
    const float* Wdt  = (const float*)d_in[5];
    const float* dtb  = (const float*)d_in[6];
    const float* Alog = (const float*)d_in[7];
    const float* Dp   = (const float*)d_in[8];
    const float* Wout = (const float*)d_in[9];
    float* out = (float*)d_out;

    const size_t SZ = (size_t)N_B * L_SEQ * D_I;        // 8,388,608
    const size_t NT = (size_t)N_B * L_SEQ;              // 4096 tokens
    const size_t NHS  = (size_t)NT * D_M;               // 4,194,304 (hs, Win each)
    const size_t NWIN = (size_t)2 * D_I * D_M;          // 4,194,304
    const size_t NWOUT = (size_t)D_M * D_I;             // 2,097,152
    const size_t NEED = SZ * 2 * sizeof(bf16)                       // RA+RB
                      + (NHS + NWIN + NWOUT) * sizeof(u16)          // bf16 copies
                      + NT * (R_DT + 2 * D_ST) * sizeof(float);     // smalls
    if (ws_size < NEED) {    // diagnostic: absmax prints exactly 2.375
        zfill<<<dim3((unsigned)((size_t)out_size / 256)), 256, 0, stream>>>(out);
        return;
    }

    bf16* RA   = (bf16*)d_ws;          // x -> delta -> y(gated)
    bf16* RB   = RA + SZ;              // u -> z
    u16* bhs   = (u16*)(RB + SZ);      // bf16 hs       [4096][1024]
    u16* bWin  = bhs + NHS;            // bf16 W_in     [4096][1024]
    u16* bWout = bWin + NWIN;          // bf16 W_out    [1024][2048]
    float* dtlr = (float*)(bWout + NWOUT);              // [4096][64]
    float* Bm   = dtlr + NT * R_DT;    // [4096][16]
    float* Cm   = Bm + NT * D_ST;      // [4096][16]
    const size_t PQ = (size_t)N_B * CHNK * D_I * D_ST;  // 4 MB each
    float* Pc  = out;                  // scan scratch in d_out (dead until final GEMM)
    float* Qc  = Pc + PQ;
    float* Sin = Qc + PQ;

    // 0) one-time fp32 -> bf16 conversions
    cvt_k<<<dim3((unsigned)(NHS / 2048)), 256, 0, stream>>>(hs, bhs);
    cvt_k<<<dim3((unsigned)(NWIN / 2048)), 256, 0, stream>>>(Win, bWin);
    cvt_k<<<dim3((unsigned)(NWOUT / 2048)), 256, 0, stream>>>(Wout, bWout);
    // 1) in_proj x-half: x = hs @ W_in[0:D_I]^T -> RA
    bgemm<0><<<dim3(32, 16), 256, 0, stream>>>(
        bhs, D_M, bWin, D_M, D_M, (u16*)RA, nullptr);
    // 2) conv + silu: RA(x) -> RB(u)
    conv_k<<<dim3(N_B * L_SEQ), 256, 0, stream>>>(RA, cw, cb, RB);
    // 3) x_proj -> dtlr/Bm/Cm
    gemm_k<bf16, 1><<<dim3(64, 2), 256, 0, stream>>>(
        RB, D_I, Wx, D_I, 96, D_I, dtlr, Bm, Cm, nullptr, nullptr);
    // 4) dt -> delta (RA, over dead x)
    gemm_k<float, 2><<<dim3(64, 32), 256, 0, stream>>>(
        dtlr, R_DT, Wdt, R_DT, D_I, R_DT, nullptr, nullptr, nullptr, RA, dtb);
    // 5) chunked scan: P,Q -> prefix -> replay (y over delta in RA)
    scan_chunk<0><<<dim3(D_I / 64, N_B, CHNK), 256, 0, stream>>>(
        RA, RB, Bm, Cm, Alog, Dp, Pc, Qc, nullptr);
    scan_comb<<<dim3(D_I / 16, N_B), 256, 0, stream>>>(Pc, Qc, Sin);
    scan_chunk<1><<<dim3(D_I / 64, N_B, CHNK), 256, 0, stream>>>(
        RA, RB, Bm, Cm, Alog, Dp, nullptr, nullptr, Sin);
    // 6) in_proj z-half: z = hs @ W_in[D_I:]^T -> RB (over dead u)
    bgemm<0><<<dim3(32, 16), 256, 0, stream>>>(
        bhs, D_M, bWin + (size_t)D_I * D_M, D_M, D_M, (u16*)RB, nullptr);
    // 6b) gate in place: y *= silu(z)
    gate_k<<<dim3((unsigned)(SZ / 2048)), 256, 0, stream>>>((u16*)RA, (const u16*)RB);
    // 7) out_proj: out = y_gated @ W_out^T -> d_out (fp32)
    bgemm<1><<<dim3(32, 8), 256, 0, stream>>>(
        (const u16*)RA, D_I, bWout, D_I, D_I, nullptr, out);
}

// Round 10
// 361.231 us; speedup vs baseline: 6.2350x; 1.2516x over previous
//
#include <hip/hip_runtime.h>
#include <hip/hip_bf16.h>

// Mamba block forward, MI355X. Round 10: fix x_proj (123us @ 5.8% occupancy,
// 128 blocks) via split-K MFMA (512 blocks, partials in d_out + reduce), and
// dt GEMM via MFMA bgemm (EPI2 softplus). Everything else from round 9.
// ws (53.7 MiB): RA | RB | bhs | bWin | bWout | bWx | bWdt | dtlr(bf16) | Bm | Cm.
// L=2048, B=2, D_MODEL=1024, D_INNER=2048, D_STATE=16, DT_RANK=64, D_CONV=4.

#define L_SEQ 2048
#define N_B   2
#define D_M   1024
#define D_I   2048
#define D_ST  16
#define R_DT  64
#define CHNK  16
#define CT    128
#define KS    8           // x_proj split-K chunks (K chunk = 256)

using bf16 = __hip_bfloat16;
typedef unsigned short u16;
typedef u16 u16x8 __attribute__((ext_vector_type(8)));
typedef __bf16 bf16x8 __attribute__((ext_vector_type(8)));
typedef float f32x4 __attribute__((ext_vector_type(4)));

__device__ __forceinline__ float b2f(u16 u) {
    union { unsigned int i; float f; } x;
    x.i = ((unsigned int)u) << 16;
    return x.f;
}
__device__ __forceinline__ u16 f2b(float f) {
    union { bf16 h; u16 s; } x;
    x.h = __float2bfloat16(f);
    return x.s;
}

__device__ __forceinline__ void load4(const float* p, float* o) {
    const float4 v = *(const float4*)p;
    o[0] = v.x; o[1] = v.y; o[2] = v.z; o[3] = v.w;
}
__device__ __forceinline__ void load4(const bf16* p, float* o) {
    const ushort4 v = *(const ushort4*)(const void*)p;
    o[0] = b2f(v.x); o[1] = b2f(v.y); o[2] = b2f(v.z); o[3] = b2f(v.w);
}

__device__ __forceinline__ float softplus_f(float x) {
    return (x > 20.f) ? x : log1pf(__expf(x));
}
__device__ __forceinline__ float silu_f(float x) {
    return x / (1.f + __expf(-x));
}

__device__ __forceinline__ void gl_lds16(const u16* g, u16* l) {
    __builtin_amdgcn_global_load_lds(
        (const __attribute__((address_space(1))) void*)g,
        (__attribute__((address_space(3))) void*)l, 16, 0, 0);
}

// ---------------- async bf16 MFMA GEMM ----------------
// C[m][n] = sum_k A[m][k]*Wb[n][k]. 128x128 tile, BK=32, XOR-swizzled LDS.
// EPI 0: bf16 bd[t][col], rows r=l*B+b -> t=b*L+l   (in_proj halves)
// EPI 1: fp32 out[l][b][col], rows t=b*L+l           (out_proj)
// EPI 2: bf16 bd[t][col] = softplus(acc + bias[col]) (dt; rows already t)
template <int EPI>
__global__ __launch_bounds__(256) void bgemm(
    const u16* __restrict__ A, int lda,
    const u16* __restrict__ Wb, int ldb, int K,
    u16* __restrict__ bd, float* __restrict__ fout,
    const float* __restrict__ bias)
{
    __shared__ u16 As[128 * 32];
    __shared__ u16 Bs[128 * 32];

    const int tid = threadIdx.x;
    const int m0 = blockIdx.x * 128;
    const int n0 = blockIdx.y * 128;
    const int w  = tid >> 6;
    const int ln = tid & 63;

    const int sr0 = (w << 4) + (ln >> 2);
    const int sr1 = sr0 + 64;
    const int sx  = ln & 3;
    const int qa0 = (sx - (sr0 >> 1)) & 3;
    const int qa1 = (sx - (sr1 >> 1)) & 3;

    const u16* ga0 = A  + (size_t)(m0 + sr0) * lda + qa0 * 8;
    const u16* ga1 = A  + (size_t)(m0 + sr1) * lda + qa1 * 8;
    const u16* gb0 = Wb + (size_t)(n0 + sr0) * ldb + qa0 * 8;
    const u16* gb1 = Wb + (size_t)(n0 + sr1) * ldb + qa1 * 8;
    u16* la0 = As + ((w << 4) + 0) * 32;
    u16* la1 = As + ((w << 4) + 64) * 32;
    u16* lb0 = Bs + ((w << 4) + 0) * 32;
    u16* lb1 = Bs + ((w << 4) + 64) * 32;

    const int wr = (w >> 1) << 6;
    const int wc = (w & 1) << 6;
    const int lm = ln & 15;
    const int qf = ln >> 4;
    int aoff[4], boff[4];
#pragma unroll
    for (int i = 0; i < 4; ++i) {
        const int ra = wr + i * 16 + lm;
        aoff[i] = ra * 32 + (((qf + (ra >> 1)) & 3) << 3);
        const int rb = wc + i * 16 + lm;
        boff[i] = rb * 32 + (((qf + (rb >> 1)) & 3) << 3);
    }

    f32x4 acc[4][4] = {};

    for (int k0 = 0; k0 < K; k0 += 32) {
        if (k0) __syncthreads();
        gl_lds16(ga0 + k0, la0);
        gl_lds16(ga1 + k0, la1);
        gl_lds16(gb0 + k0, lb0);
        gl_lds16(gb1 + k0, lb1);
        __syncthreads();

        bf16x8 af[4], bf[4];
#pragma unroll
        for (int i = 0; i < 4; ++i) af[i] = *(const bf16x8*)&As[aoff[i]];
#pragma unroll
        for (int j = 0; j < 4; ++j) bf[j] = *(const bf16x8*)&Bs[boff[j]];
#pragma unroll
        for (int i = 0; i < 4; ++i)
#pragma unroll
            for (int j = 0; j < 4; ++j)
                acc[i][j] = __builtin_amdgcn_mfma_f32_16x16x32_bf16(
                    af[i], bf[j], acc[i][j], 0, 0, 0);
    }

    const int qr = (ln >> 4) << 2;
    float bv[4];
    if (EPI == 2) {
#pragma unroll
        for (int j = 0; j < 4; ++j) bv[j] = bias[n0 + wc + j * 16 + lm];
    }
#pragma unroll
    for (int i = 0; i < 4; ++i) {
#pragma unroll
        for (int reg = 0; reg < 4; ++reg) {
            const int rg = m0 + wr + i * 16 + qr + reg;
            if (EPI == 0) {
                const int bb = rg & (N_B - 1);
                const int l = rg >> 1;
                const size_t t = (size_t)bb * L_SEQ + l;
#pragma unroll
                for (int j = 0; j < 4; ++j)
                    bd[t * D_I + n0 + wc + j * 16 + lm] = f2b(acc[i][j][reg]);
            } else if (EPI == 1) {
                const int bb = rg >> 11;
                const int l = rg & (L_SEQ - 1);
                const size_t o = ((size_t)l * N_B + bb) * D_M;
#pragma unroll
                for (int j = 0; j < 4; ++j)
                    fout[o + n0 + wc + j * 16 + lm] = acc[i][j][reg];
            } else {
                const size_t t = (size_t)rg;
#pragma unroll
                for (int j = 0; j < 4; ++j)
                    bd[t * D_I + n0 + wc + j * 16 + lm] =
                        f2b(softplus_f(acc[i][j][reg] + bv[j]));
            }
        }
    }
}

// ---------------- x_proj split-K MFMA ----------------
// Part[kc][t][c] = sum_{k in chunk kc} u[t][k] * Wxb[c][k]; c < 96.
// grid (M/64=64, KS), block 256 = 4 waves; wave w = 16 tokens x 96 cols.
// B chunk (96x256) staged once (padded stride 264); A staged per BK=32 via
// global_load_lds with XOR swizzle.
__global__ __launch_bounds__(256) void xproj_k(
    const u16* __restrict__ u, const u16* __restrict__ Wxb,
    float* __restrict__ Part)
{
    __shared__ u16 As[64 * 32];
    __shared__ u16 Bs[96 * 264];

    const int tid = threadIdx.x;
    const int m0 = blockIdx.x * 64;
    const int kc = blockIdx.y;
    const int kbase = kc * 256;

    // stage whole B chunk once (12 b128 per thread)
    for (int e = tid; e < 96 * 32; e += 256) {
        const int row = e >> 5, kq = e & 31;
        const u16x8 v = *(const u16x8*)(Wxb + (size_t)row * D_I + kbase + kq * 8);
        *(u16x8*)&Bs[row * 264 + kq * 8] = v;
    }

    const int w  = tid >> 6;
    const int ln = tid & 63;
    const int sr = (w << 4) + (ln >> 2);          // A staging row 0..63
    const int sx = ln & 3;
    const int qa = (sx - (sr >> 1)) & 3;
    const u16* ga = u + (size_t)(m0 + sr) * D_I + kbase + qa * 8;
    u16* la = As + (w << 9);                      // wave-uniform base

    const int lm = ln & 15;
    const int qf = ln >> 4;
    const int ra = (w << 4) + lm;                 // this wave's A row
    const int aoff = ra * 32 + (((qf + (ra >> 1)) & 3) << 3);

    f32x4 acc[6] = {};

    for (int it = 0; it < 8; ++it) {
        if (it) __syncthreads();
        gl_lds16(ga + it * 32, la);
        __syncthreads();

        const bf16x8 af = *(const bf16x8*)&As[aoff];
#pragma unroll
        for (int j = 0; j < 6; ++j) {
            const bf16x8 bf = *(const bf16x8*)&Bs[(j * 16 + lm) * 264 + it * 32 + qf * 8];
            acc[j] = __builtin_amdgcn_mfma_f32_16x16x32_bf16(af, bf, acc[j], 0, 0, 0);
        }
    }

    const int qr = (ln >> 4) << 2;
#pragma unroll
    for (int j = 0; j < 6; ++j) {
#pragma unroll
        for (int reg = 0; reg < 4; ++reg) {
            const int t = m0 + (w << 4) + qr + reg;
            Part[((size_t)kc * (N_B * L_SEQ) + t) * 96 + j * 16 + lm] = acc[j][reg];
        }
    }
}

// reduce split-K partials + split96: dtlr (bf16) / Bm / Cm (fp32)
__global__ __launch_bounds__(256) void xreduce(
    const float* __restrict__ Part, u16* __restrict__ dtlr,
    float* __restrict__ Bm, float* __restrict__ Cm)
{
    const int e = blockIdx.x * 256 + threadIdx.x;   // < 4096*96
    const int t = e / 96, c = e - t * 96;
    float s = 0.f;
#pragma unroll
    for (int kc = 0; kc < KS; ++kc)
        s += Part[(size_t)kc * (N_B * L_SEQ * 96) + e];
    if (c < 64)      dtlr[t * 64 + c] = f2b(s);
    else if (c < 80) Bm[t * 16 + (c - 64)] = s;
    else             Cm[t * 16 + (c - 80)] = s;
}

// fp32 -> bf16 one-time conversion (8 elems/thread)
__global__ __launch_bounds__(256) void cvt_k(const float* __restrict__ s,
                                             u16* __restrict__ d)
{
    const size_t i = ((size_t)blockIdx.x * 256 + threadIdx.x) * 8;
    const float4 a = *(const float4*)(s + i);
    const float4 b = *(const float4*)(s + i + 4);
    u16 t[8] = {f2b(a.x), f2b(a.y), f2b(a.z), f2b(a.w),
                f2b(b.x), f2b(b.y), f2b(b.z), f2b(b.w)};
    *(u16x8*)(d + i) = *(const u16x8*)t;
}

// y *= silu(z), in place (8 elems/thread)
__global__ __launch_bounds__(256) void gate_k(u16* __restrict__ y,
                                              const u16* __restrict__ z)
{
    const size_t i = ((size_t)blockIdx.x * 256 + threadIdx.x) * 8;
    u16x8 yv = *(u16x8*)(y + i);
    const u16x8 zv = *(const u16x8*)(z + i);
    u16 t[8];
#pragma unroll
    for (int j = 0; j < 8; ++j)
        t[j] = f2b(b2f(yv[j]) * silu_f(b2f(zv[j])));
    *(u16x8*)(y + i) = *(const u16x8*)t;
}

// ---------------- conv ----------------
__global__ __launch_bounds__(256) void conv_k(
    const bf16* __restrict__ x, const float* __restrict__ cw,
    const float* __restrict__ cb, bf16* __restrict__ xc)
{
    const int t = blockIdx.x;
    const int l = t & (L_SEQ - 1);
#pragma unroll
    for (int it = 0; it < 2; ++it) {
        const int d = ((int)threadIdx.x + it * 256) << 2;
        float w[4][4], bias[4], acc[4];
#pragma unroll
        for (int dd = 0; dd < 4; ++dd)
            load4(cw + (size_t)(d + dd) * 4, w[dd]);
        load4(cb + d, bias);
#pragma unroll
        for (int dd = 0; dd < 4; ++dd) acc[dd] = bias[dd];
#pragma unroll
        for (int j = 0; j < 4; ++j) {
            const int ll = l - 3 + j;
            if (ll >= 0) {
                float xv[4];
                load4(x + (size_t)(t - 3 + j) * D_I + d, xv);
#pragma unroll
                for (int dd = 0; dd < 4; ++dd)
                    acc[dd] = fmaf(xv[dd], w[dd][j], acc[dd]);
            }
        }
        const ushort4 v = make_ushort4(f2b(silu_f(acc[0])), f2b(silu_f(acc[1])),
                                       f2b(silu_f(acc[2])), f2b(silu_f(acc[3])));
        *(ushort4*)(void*)(xc + (size_t)t * D_I + d) = v;
    }
}

// ---------------- chunked scan (register-state) ----------------
template <int PHASE>
__global__ __launch_bounds__(256) void scan_chunk(
    bf16* __restrict__ dy, const bf16* __restrict__ u,
    const float* __restrict__ Bm, const float* __restrict__ Cm,
    const float* __restrict__ Alog, const float* __restrict__ Dp,
    float* __restrict__ Pc, float* __restrict__ Qc,
    const float* __restrict__ Sin)
{
    __shared__ float Bs[CT][D_ST];
    __shared__ float Cs[(PHASE == 1) ? CT : 1][D_ST];

    const int tid = threadIdx.x;
    const int b  = blockIdx.y;
    const int c  = blockIdx.z;
    const int row0 = b * L_SEQ + c * CT;

    {
        const float4* src = (const float4*)(Bm + (size_t)row0 * D_ST);
        float4* dst = (float4*)Bs;
        for (int e = tid; e < CT * D_ST / 4; e += 256) dst[e] = src[e];
        if (PHASE == 1) {
            const float4* s2 = (const float4*)(Cm + (size_t)row0 * D_ST);
            float4* d2 = (float4*)Cs;
            for (int e = tid; e < CT * D_ST / 4; e += 256) d2[e] = s2[e];
        }
    }
    __syncthreads();

    const int d  = blockIdx.x * 64 + (tid >> 2);
    const int ns = tid & 3;
    const size_t pqbase = (((size_t)b * CHNK + c) * D_I + d) * D_ST + ns * 4;

    float Av[4];
    {
        const float4 a4 = *(const float4*)(Alog + (size_t)d * D_ST + ns * 4);
        Av[0] = -__expf(a4.x); Av[1] = -__expf(a4.y);
        Av[2] = -__expf(a4.z); Av[3] = -__expf(a4.w);
    }

    float st[4] = {0.f, 0.f, 0.f, 0.f};
    float P[4]  = {1.f, 1.f, 1.f, 1.f};
    if (PHASE == 1) {
        const float4 s0 = *(const float4*)(Sin + pqbase);
        st[0] = s0.x; st[1] = s0.y; st[2] = s0.z; st[3] = s0.w;
    }
    const float Dd = (PHASE == 1) ? Dp[d] : 0.f;

    const bf16* up = u + (size_t)row0 * D_I + d;
    bf16* dp = dy + (size_t)row0 * D_I + d;

    float dv0 = __bfloat162float(dp[0]);
    float uv0 = __bfloat162float(up[0]);
    float dv1 = __bfloat162float(dp[D_I]);
    float uv1 = __bfloat162float(up[D_I]);

    for (int l = 0; l < CT; ++l) {
        const int lp = (l + 2 < CT) ? (l + 2) : (CT - 1);
        const float dvn = __bfloat162float(dp[(size_t)lp * D_I]);
        const float uvn = __bfloat162float(up[(size_t)lp * D_I]);

        const float dv = dv0, uv = uv0;
        const float dvu = dv * uv;
        float bn[4], cn[4] = {0.f, 0.f, 0.f, 0.f};
        {
            const float4 b4 = *(const float4*)&Bs[l][ns * 4];
            bn[0] = b4.x; bn[1] = b4.y; bn[2] = b4.z; bn[3] = b4.w;
        }
        if (PHASE == 1) {
            const float4 c4 = *(const float4*)&Cs[l][ns * 4];
            cn[0] = c4.x; cn[1] = c4.y; cn[2] = c4.z; cn[3] = c4.w;
        }

        float y = 0.f;
#pragma unroll
        for (int j = 0; j < 4; ++j) {
            const float dA = __expf(dv * Av[j]);
            if (PHASE == 0) P[j] *= dA;
            st[j] = fmaf(st[j], dA, dvu * bn[j]);
            if (PHASE == 1) y = fmaf(st[j], cn[j], y);
        }
        if (PHASE == 1) {
            y += __shfl_xor(y, 1);
            y += __shfl_xor(y, 2);
            if (ns == 0)
                dp[(size_t)l * D_I] = __float2bfloat16(y + uv * Dd);
        }
        dv0 = dv1; uv0 = uv1; dv1 = dvn; uv1 = uvn;
    }

    if (PHASE == 0) {
        *(float4*)(Pc + pqbase) = make_float4(P[0], P[1], P[2], P[3]);
        *(float4*)(Qc + pqbase) = make_float4(st[0], st[1], st[2], st[3]);
    }
}

__global__ __launch_bounds__(256) void scan_comb(
    const float* __restrict__ Pc, const float* __restrict__ Qc,
    float* __restrict__ Sin)
{
    const int b = blockIdx.y;
    const int d = blockIdx.x * 16 + (threadIdx.x >> 4);
    const int n = threadIdx.x & 15;
    float s = 0.f;
#pragma unroll
    for (int c = 0; c < CHNK; ++c) {
        const size_t idx = (((size_t)b * CHNK + c) * D_I + d) * D_ST + n;
        Sin[idx] = s;
        s = fmaf(s, Pc[idx], Qc[idx]);
    }
}

__global__ void zfill(float* o) {
    o[(size_t)blockIdx.x * 256 + threadIdx.x] = 0.f;
}

extern "C" void kernel_launch(void* const* d_in, const int* in_sizes, int n_in,
                              void* d_out, int out_size, void* d_ws, size_t ws_size,
                              hipStream_t stream)
{
    const float* hs   = (const float*)d_in[0];
    const float* Win  = (const float*)d_in[1];
    const float* cw   = (const float*)d_in[2];
    const float* cb   = (const float*)d_in[3];
    const float* Wx   = (const float*)d_in[4];
    const float* Wdt  = (const float*)d_in[5];
    const float* dtb  = (const float*)d_in[6];
    const float* Alog = (const float*)d_in[7];
    const float* Dp   = (const float*)d_in[8];
    const float* Wout = (const float*)d_in[9];
    float* out = (float*)d_out;

    const size_t SZ = (size_t)N_B * L_SEQ * D_I;        // 8,388,608
    const size_t NT = (size_t)N_B * L_SEQ;              // 4096 tokens
    const size_t NHS   = NT * D_M;                      // 4,194,304
    const size_t NWIN  = (size_t)2 * D_I * D_M;         // 4,194,304
    const size_t NWOUT = (size_t)D_M * D_I;             // 2,097,152
    const size_t NWX   = (size_t)96 * D_I;              // 196,608
    const size_t NWDT  = (size_t)D_I * R_DT;            // 131,072
    const size_t NEED = SZ * 2 * sizeof(bf16)
                      + (NHS + NWIN + NWOUT + NWX + NWDT + NT * R_DT) * sizeof(u16)
                      + NT * 2 * D_ST * sizeof(float);
    if (ws_size < NEED) {   // diagnostic: absmax would print exactly 2.375
        zfill<<<dim3((unsigned)((size_t)out_size / 256)), 256, 0, stream>>>(out);
        return;
    }

    bf16* RA   = (bf16*)d_ws;          // x -> delta -> y(gated)
    bf16* RB   = RA + SZ;              // u -> z
    u16* bhs   = (u16*)(RB + SZ);      // bf16 hs     [4096][1024]
    u16* bWin  = bhs + NHS;            // bf16 W_in   [4096][1024]
    u16* bWout = bWin + NWIN;          // bf16 W_out  [1024][2048]
    u16* bWx   = bWout + NWOUT;        // bf16 W_x    [96][2048]
    u16* bWdt  = bWx + NWX;            // bf16 W_dt   [2048][64]
    u16* dtlr  = bWdt + NWDT;          // bf16 dtlr   [4096][64]
    float* Bm  = (float*)(dtlr + NT * R_DT);            // [4096][16]
    float* Cm  = Bm + NT * D_ST;                        // [4096][16]
    // d_out scratch: Part (12.6 MB) for x_proj, then Pc/Qc/Sin (12 MB) for scan
    float* Part = out;                 // [KS][4096][96]
    const size_t PQ = (size_t)N_B * CHNK * D_I * D_ST;
    float* Pc  = out;
    float* Qc  = Pc + PQ;
    float* Sin = Qc + PQ;

    // 0) one-time fp32 -> bf16 conversions
    cvt_k<<<dim3((unsigned)(NHS / 2048)), 256, 0, stream>>>(hs, bhs);
    cvt_k<<<dim3((unsigned)(NWIN / 2048)), 256, 0, stream>>>(Win, bWin);
    cvt_k<<<dim3((unsigned)(NWOUT / 2048)), 256, 0, stream>>>(Wout, bWout);
    cvt_k<<<dim3((unsigned)(NWX / 2048)), 256, 0, stream>>>(Wx, bWx);
    cvt_k<<<dim3((unsigned)(NWDT / 2048)), 256, 0, stream>>>(Wdt, bWdt);
    // 1) in_proj x-half: x = hs @ W_in[0:D_I]^T -> RA
    bgemm<0><<<dim3(32, 16), 256, 0, stream>>>(
        bhs, D_M, bWin, D_M, D_M, (u16*)RA, nullptr, nullptr);
    // 2) conv + silu: RA(x) -> RB(u)
    conv_k<<<dim3(N_B * L_SEQ), 256, 0, stream>>>(RA, cw, cb, RB);
    // 3) x_proj split-K -> Part, then reduce -> dtlr/Bm/Cm
    xproj_k<<<dim3(64, KS), 256, 0, stream>>>((const u16*)RB, bWx, Part);
    xreduce<<<dim3((unsigned)(NT * 96 / 256)), 256, 0, stream>>>(Part, dtlr, Bm, Cm);
    // 4) dt: delta = softplus(dtlr @ W_dt^T + dtb) -> RA (MFMA, K=64)
    bgemm<2><<<dim3(32, 16), 256, 0, stream>>>(
        dtlr, R_DT, bWdt, R_DT, R_DT, (u16*)RA, nullptr, dtb);
    // 5) chunked scan: P,Q -> prefix -> replay (y over delta in RA)
    scan_chunk<0><<<dim3(D_I / 64, N_B, CHNK), 256, 0, stream>>>(
        RA, RB, Bm, Cm, Alog, Dp, Pc, Qc, nullptr);
    scan_comb<<<dim3(D_I / 16, N_B), 256, 0, stream>>>(Pc, Qc, Sin);
    scan_chunk<1><<<dim3(D_I / 64, N_B, CHNK), 256, 0, stream>>>(
        RA, RB, Bm, Cm, Alog, Dp, nullptr, nullptr, Sin);
    // 6) in_proj z-half: z = hs @ W_in[D_I:]^T -> RB (over dead u)
    bgemm<0><<<dim3(32, 16), 256, 0, stream>>>(
        bhs, D_M, bWin + (size_t)D_I * D_M, D_M, D_M, (u16*)RB, nullptr, nullptr);
    // 6b) gate in place: y *= silu(z)
    gate_k<<<dim3((unsigned)(SZ / 2048)), 256, 0, stream>>>((u16*)RA, (const u16*)RB);
    // 7) out_proj: out = y_gated @ W_out^T -> d_out (fp32)
    bgemm<1><<<dim3(32, 8), 256, 0, stream>>>(
        (const u16*)RA, D_I, bWout, D_I, D_I, nullptr, out, nullptr);
}